// Round 6
// baseline (2398.772 us; speedup 1.0000x reference)
//
#include <hip/hip_runtime.h>
#include <stdint.h>

typedef float    f32x4  __attribute__((ext_vector_type(4)));
typedef __bf16   bf16x8 __attribute__((ext_vector_type(8)));
typedef uint16_t u16x8  __attribute__((ext_vector_type(8)));
typedef uint16_t u16x4  __attribute__((ext_vector_type(4)));

static __device__ __forceinline__ f32x4 mfma_bf16(bf16x8 a, bf16x8 b, f32x4 c) {
  return __builtin_amdgcn_mfma_f32_16x16x32_bf16(a, b, c, 0, 0, 0);
}
// fp32 -> bf16 round-to-nearest-even
static __device__ __forceinline__ uint16_t f2bf(float f) {
  uint32_t u = __builtin_bit_cast(uint32_t, f);
  u += 0x7fffu + ((u >> 16) & 1u);
  return (uint16_t)(u >> 16);
}

constexpr int Nrows = 131072;
constexpr int Dk    = 128;
constexpr int Cc    = 1024;
constexpr int BM    = 64;    // rows of x per block
constexpr int BN    = 256;   // output cols per block
constexpr int KB    = 128;   // c-dim step
constexpr int NCB   = Cc / BN;                 // 4
constexpr int XBYTES = BM * Dk * 2;            // 16384
constexpr int PBYTES = BM * KB * 2;            // 16384
constexpr int LDS_MAIN = XBYTES + PBYTES + BM * 4;  // 33024
constexpr int LDS_FB   = LDS_MAIN + Cc * 4;         // fallback adds c2[1024]

// ---------------------------------------------------------------------------
// Prep A: centers -> bf16 [C][D], and c2[C] = ||c||^2
// ---------------------------------------------------------------------------
__global__ void prep_cen(const float* __restrict__ cen,
                         uint16_t* __restrict__ cenb,
                         float* __restrict__ c2) {
  const int t = threadIdx.x;
  const int row = blockIdx.x * 16 + (t >> 4);
  const int q = t & 15;
  const float* src = cen + (size_t)row * Dk + q * 8;
  f32x4 v0 = *(const f32x4*)src;
  f32x4 v1 = *(const f32x4*)(src + 4);
  u16x8 h;
  float ss = 0.f;
#pragma unroll
  for (int i = 0; i < 4; ++i) {
    h[i]     = f2bf(v0[i]); ss += v0[i] * v0[i];
    h[i + 4] = f2bf(v1[i]); ss += v1[i] * v1[i];
  }
  *(u16x8*)(cenb + (size_t)row * Dk + q * 8) = h;
  ss += __shfl_xor(ss, 1);
  ss += __shfl_xor(ss, 2);
  ss += __shfl_xor(ss, 4);
  ss += __shfl_xor(ss, 8);
  if (q == 0) c2[row] = ss;
}

// ---------------------------------------------------------------------------
// Prep B: nT[j][c] = bf16(norm[c][j])
// ---------------------------------------------------------------------------
__global__ void prep_nT(const float* __restrict__ nrm, uint16_t* __restrict__ nT) {
  __shared__ float tile[64][65];
  const int jb = blockIdx.x & 15;
  const int cb = blockIdx.x >> 4;
  const int t  = threadIdx.x;
  const int r  = t >> 4;
  const int q  = t & 15;
#pragma unroll
  for (int i = 0; i < 4; ++i) {
    int row = r + i * 16;  // c within tile
    f32x4 v = *(const f32x4*)(nrm + (size_t)(cb * 64 + row) * Cc + jb * 64 + q * 4);
#pragma unroll
    for (int s = 0; s < 4; ++s) tile[row][q * 4 + s] = v[s];
  }
  __syncthreads();
#pragma unroll
  for (int i = 0; i < 4; ++i) {
    int j = r + i * 16;  // j within tile
    u16x4 hs;
#pragma unroll
    for (int s = 0; s < 4; ++s) hs[s] = f2bf(tile[q * 4 + s][j]);
    *(u16x4*)(nT + (size_t)(jb * 64 + j) * Cc + cb * 64 + q * 4) = hs;
  }
}

// ---------------------------------------------------------------------------
// Fused main: per block out[64 x 256]. c-loop (KB=128):
//   GEMM1 cross = x@cen^T -> P=exp(-g*sqd) -> LDS -> GEMM2 acc += P@nT
// R6: B-operands batch-loaded into registers before each MFMA burst; the 16
// nT loads are issued BEFORE the P-phase so their L2 latency hides under
// exp/cvt work + barrier instead of serializing with GEMM2's MFMAs.
// ---------------------------------------------------------------------------
template <int USE_NT>
__global__ __launch_bounds__(512, 4) void nyst_main(
    const float* __restrict__ x, const float* __restrict__ cen,
    const float* __restrict__ gam, const float* __restrict__ nrm,
    const uint16_t* __restrict__ cenb, const float* __restrict__ c2g,
    const uint16_t* __restrict__ nT, float* __restrict__ out) {
  extern __shared__ char smem[];
  char*  xB  = smem;                              // [64][128] bf16, swizzled
  char*  pB  = smem + XBYTES;                     // [64][128] bf16, swizzled
  float* x2s = (float*)(smem + XBYTES + PBYTES);  // [64]
  float* c2s = (float*)(smem + LDS_MAIN);         // [1024], fallback only

  const int tid  = threadIdx.x;
  const int lane = tid & 63;
  const int wid  = tid >> 6;
  const int wr   = wid >> 2;  // 0..1  (row half)
  const int wc   = wid & 3;   // 0..3  (col quarter)
  // XCD-pinned decomposition: xcd = blockIdx%8; pair {2k,2k+1} owns colb=k.
  const int xcd  = blockIdx.x & 7;
  const int bi   = blockIdx.x >> 3;          // 0..1023
  const int colb = xcd >> 1;                 // 0..3
  const int rowb = (bi << 1) | (xcd & 1);    // 0..2047
  const int l15  = lane & 15;
  const int l4   = lane >> 4;

  const float* xblk = x + (size_t)rowb * BM * Dk;

  // ---- stage x tile as bf16 into swizzled LDS (nt loads); fuse x2 row-sums --
#pragma unroll
  for (int it = 0; it < 2; ++it) {
    int ch = tid + it * 512;   // 1024 chunks of 8 elems
    int r  = ch >> 4;          // row 0..63
    int cc = ch & 15;          // 16B chunk in row
    const float* src = xblk + r * Dk + cc * 8;
    f32x4 v0 = __builtin_nontemporal_load((const f32x4*)src);
    f32x4 v1 = __builtin_nontemporal_load((const f32x4*)(src + 4));
    u16x8 hh;
    float ss = 0.f;
#pragma unroll
    for (int i = 0; i < 4; ++i) {
      hh[i]     = f2bf(v0[i]); ss += v0[i] * v0[i];
      hh[i + 4] = f2bf(v1[i]); ss += v1[i] * v1[i];
    }
    int off = (r * 256 + cc * 16) ^ ((r & 7) << 4);
    *(u16x8*)(xB + off) = hh;
    ss += __shfl_xor(ss, 1);
    ss += __shfl_xor(ss, 2);
    ss += __shfl_xor(ss, 4);
    ss += __shfl_xor(ss, 8);
    if ((tid & 15) == 0) x2s[r] = ss;
  }
  if (!USE_NT) {
#pragma unroll
    for (int rr = 0; rr < 2; ++rr) {
      int r = tid + rr * 512;
      const float* src = cen + (size_t)r * Dk;
      float ss = 0.f;
      for (int k = 0; k < Dk / 4; ++k) {
        f32x4 v = *(const f32x4*)(src + 4 * k);
        ss += v[0] * v[0] + v[1] * v[1] + v[2] * v[2] + v[3] * v[3];
      }
      c2s[r] = ss;
    }
  }
  __syncthreads();

  const float ngam = -gam[0];
  f32x4 zero4 = {0.f, 0.f, 0.f, 0.f};
  f32x4 acc[2][4];
#pragma unroll
  for (int m = 0; m < 2; ++m)
#pragma unroll
    for (int n = 0; n < 4; ++n) acc[m][n] = zero4;

  for (int c0 = 0; c0 < Cc; c0 += KB) {
    // ===== GEMM1: batch-load 8 cenb fragments, then 16-MFMA burst =====
    f32x4 cr[2][2];  // [g][m]
#pragma unroll
    for (int g = 0; g < 2; ++g)
#pragma unroll
      for (int m = 0; m < 2; ++m) cr[g][m] = zero4;

    bf16x8 b[4][2];  // [kk][g] : 32 VGPR
    if (USE_NT) {
      const uint16_t* cb0 = cenb + (size_t)(c0 + 16 * wc + l15) * Dk + l4 * 8;
#pragma unroll
      for (int kk = 0; kk < 4; ++kk) {
        b[kk][0] = *(const bf16x8*)(cb0 + kk * 32);
        b[kk][1] = *(const bf16x8*)(cb0 + 64 * Dk + kk * 32);
      }
    } else {
#pragma unroll
      for (int kk = 0; kk < 4; ++kk) {
#pragma unroll
        for (int g = 0; g < 2; ++g) {
          int ccol = c0 + g * 64 + 16 * wc + l15;
          const float* cb_ = cen + (size_t)ccol * Dk + kk * 32 + l4 * 8;
          f32x4 v0 = *(const f32x4*)cb_;
          f32x4 v1 = *(const f32x4*)(cb_ + 4);
          u16x8 tt;
#pragma unroll
          for (int i = 0; i < 4; ++i) { tt[i] = f2bf(v0[i]); tt[i + 4] = f2bf(v1[i]); }
          b[kk][g] = __builtin_bit_cast(bf16x8, tt);
        }
      }
    }
#pragma unroll
    for (int kk = 0; kk < 4; ++kk) {
#pragma unroll
      for (int m = 0; m < 2; ++m) {
        int row = 32 * wr + 16 * m + l15;
        int off = (row * 256 + kk * 64 + l4 * 16) ^ ((row & 7) << 4);
        bf16x8 a = *(const bf16x8*)(xB + off);
        cr[0][m] = mfma_bf16(a, b[kk][0], cr[0][m]);
        cr[1][m] = mfma_bf16(a, b[kk][1], cr[1][m]);
      }
    }

    // ===== issue ALL 16 nT loads now: latency hides under P-phase + barrier
    bf16x8 nb[4][4];  // [kk][n] : 64 VGPR
    if (USE_NT) {
      const uint16_t* nbase =
          nT + (size_t)(colb * BN + wc * 64 + l15) * Cc + c0 + l4 * 8;
#pragma unroll
      for (int n = 0; n < 4; ++n)
#pragma unroll
        for (int kk = 0; kk < 4; ++kk)
          nb[kk][n] = *(const bf16x8*)(nbase + (size_t)(16 * n) * Cc + kk * 32);
    }

    // ===== P = exp(-g*max(x2+c2-2cross,0)) -> swizzled LDS (bf16)
    __syncthreads();  // prev GEMM2 done reading pB
#pragma unroll
    for (int g = 0; g < 2; ++g) {
      int ccol = c0 + g * 64 + 16 * wc + l15;
      float c2v = USE_NT ? c2g[ccol] : c2s[ccol];
#pragma unroll
      for (int m = 0; m < 2; ++m) {
#pragma unroll
        for (int r = 0; r < 4; ++r) {
          int row = 32 * wr + 16 * m + l4 * 4 + r;
          float s = fmaxf(fmaf(-2.f, cr[g][m][r], x2s[row] + c2v), 0.f);
          float p = __expf(ngam * s);
          int off = (row * 256 + (g * 64 + 16 * wc + l15) * 2) ^ ((row & 7) << 4);
          *(uint16_t*)(pB + off) = f2bf(p);
        }
      }
    }
    __syncthreads();

    // ===== GEMM2: LDS pa reads + 32-MFMA burst on pre-loaded nb =====
#pragma unroll
    for (int kk = 0; kk < 4; ++kk) {
      bf16x8 pa[2];
#pragma unroll
      for (int m = 0; m < 2; ++m) {
        int row = 32 * wr + 16 * m + l15;
        int off = (row * 256 + kk * 64 + l4 * 16) ^ ((row & 7) << 4);
        pa[m] = *(const bf16x8*)(pB + off);
      }
#pragma unroll
      for (int n = 0; n < 4; ++n) {
        bf16x8 bm;
        if (USE_NT) {
          bm = nb[kk][n];
        } else {
          int j    = colb * BN + wc * 64 + 16 * n + l15;
          int krow = c0 + kk * 32 + l4 * 8;
          u16x8 tt;
#pragma unroll
          for (int i = 0; i < 8; ++i) tt[i] = f2bf(nrm[(size_t)(krow + i) * Cc + j]);
          bm = __builtin_bit_cast(bf16x8, tt);
        }
        acc[0][n] = mfma_bf16(pa[0], bm, acc[0][n]);
        acc[1][n] = mfma_bf16(pa[1], bm, acc[1][n]);
      }
    }
  }

  // ===== epilogue: LDS bounce (reuse xB+pB as [32][256] f32), halves by wr ==
  float* outBuf = (float*)smem;
  const int orow0 = rowb * BM;
#pragma unroll
  for (int h = 0; h < 2; ++h) {
    __syncthreads();  // pB reads done (h=0) / prev half readers done (h=1)
    if (wr == h) {
#pragma unroll
      for (int m = 0; m < 2; ++m) {
#pragma unroll
        for (int n = 0; n < 4; ++n) {
#pragma unroll
          for (int r = 0; r < 4; ++r) {
            int rL = 16 * m + l4 * 4 + r;  // 0..31
            outBuf[rL * 256 + wc * 64 + 16 * n + l15] = acc[m][n][r];
          }
        }
      }
    }
    __syncthreads();
#pragma unroll
    for (int i = 0; i < 4; ++i) {
      int ch = tid + 512 * i;   // 2048 chunks of 16B
      int rL = ch >> 6;         // 0..31
      int c4 = ch & 63;
      f32x4 v = *(const f32x4*)(outBuf + rL * 256 + c4 * 4);
      *(f32x4*)(out + (size_t)(orow0 + 32 * h + rL) * Cc + colb * BN + c4 * 4) = v;
    }
  }
}

// ---------------------------------------------------------------------------
extern "C" void kernel_launch(void* const* d_in, const int* in_sizes, int n_in,
                              void* d_out, int out_size, void* d_ws, size_t ws_size,
                              hipStream_t stream) {
  const float* x   = (const float*)d_in[0];  // [131072,128]
  const float* cen = (const float*)d_in[1];  // [1024,128]
  const float* gam = (const float*)d_in[2];  // [1]
  const float* nrm = (const float*)d_in[3];  // [1024,1024]
  float* out = (float*)d_out;

  const size_t cenbB = (size_t)Cc * Dk * 2;  // 256 KB
  const size_t c2B   = (size_t)Cc * 4;       // 4 KB
  const size_t nTB   = (size_t)Cc * Cc * 2;  // 2 MB
  const int grid = (Nrows / BM) * NCB;       // 8192

  if (ws_size >= cenbB + c2B + nTB) {
    uint16_t* cenb = (uint16_t*)d_ws;
    float*    c2   = (float*)((char*)d_ws + cenbB);
    uint16_t* nT   = (uint16_t*)((char*)d_ws + cenbB + c2B);
    prep_cen<<<64, 256, 0, stream>>>(cen, cenb, c2);
    prep_nT<<<256, 256, 0, stream>>>(nrm, nT);
    nyst_main<1><<<grid, 512, LDS_MAIN, stream>>>(x, cen, gam, nrm, cenb, c2, nT, out);
  } else {
    nyst_main<0><<<grid, 512, LDS_FB, stream>>>(x, cen, gam, nrm, nullptr, nullptr, nullptr, out);
  }
}

// Round 7
// 707.882 us; speedup vs baseline: 3.3887x; 3.3887x over previous
//
#include <hip/hip_runtime.h>
#include <stdint.h>

typedef float    f32x4  __attribute__((ext_vector_type(4)));
typedef __bf16   bf16x8 __attribute__((ext_vector_type(8)));
typedef uint16_t u16x8  __attribute__((ext_vector_type(8)));
typedef uint16_t u16x4  __attribute__((ext_vector_type(4)));

static __device__ __forceinline__ f32x4 mfma_bf16(bf16x8 a, bf16x8 b, f32x4 c) {
  return __builtin_amdgcn_mfma_f32_16x16x32_bf16(a, b, c, 0, 0, 0);
}
// fp32 -> bf16 round-to-nearest-even
static __device__ __forceinline__ uint16_t f2bf(float f) {
  uint32_t u = __builtin_bit_cast(uint32_t, f);
  u += 0x7fffu + ((u >> 16) & 1u);
  return (uint16_t)(u >> 16);
}
// async global->LDS, 16B per lane (gfx950)
static __device__ __forceinline__ void gload16(const void* src, void* lds) {
  __builtin_amdgcn_global_load_lds(
      (const __attribute__((address_space(1))) void*)src,
      (__attribute__((address_space(3))) void*)lds, 16, 0, 0);
}

constexpr int Nrows = 131072;
constexpr int Dk    = 128;
constexpr int Cc    = 1024;
// ---- split-path geometry ----
constexpr int CH     = 16384;          // rows per chunk
constexpr int NCHUNK = Nrows / CH;     // 8
// ---- fused fallback (R5) geometry ----
constexpr int BM    = 64;
constexpr int BN    = 256;
constexpr int KB    = 128;
constexpr int NCB   = Cc / BN;                      // 4
constexpr int XBYTES = BM * Dk * 2;                 // 16384
constexpr int PBYTES = BM * KB * 2;                 // 16384
constexpr int LDS_MAIN = XBYTES + PBYTES + BM * 4;  // 33024
constexpr int LDS_FB   = LDS_MAIN + Cc * 4;

// ---------------------------------------------------------------------------
// Prep A: centers -> bf16 [C][D], and c2[C] = ||c||^2
// ---------------------------------------------------------------------------
__global__ void prep_cen(const float* __restrict__ cen,
                         uint16_t* __restrict__ cenb,
                         float* __restrict__ c2) {
  const int t = threadIdx.x;
  const int row = blockIdx.x * 16 + (t >> 4);
  const int q = t & 15;
  const float* src = cen + (size_t)row * Dk + q * 8;
  f32x4 v0 = *(const f32x4*)src;
  f32x4 v1 = *(const f32x4*)(src + 4);
  u16x8 h;
  float ss = 0.f;
#pragma unroll
  for (int i = 0; i < 4; ++i) {
    h[i]     = f2bf(v0[i]); ss += v0[i] * v0[i];
    h[i + 4] = f2bf(v1[i]); ss += v1[i] * v1[i];
  }
  *(u16x8*)(cenb + (size_t)row * Dk + q * 8) = h;
  ss += __shfl_xor(ss, 1);
  ss += __shfl_xor(ss, 2);
  ss += __shfl_xor(ss, 4);
  ss += __shfl_xor(ss, 8);
  if (q == 0) c2[row] = ss;
}

// ---------------------------------------------------------------------------
// Prep B: nT[j][c] = bf16(norm[c][j])
// ---------------------------------------------------------------------------
__global__ void prep_nT(const float* __restrict__ nrm, uint16_t* __restrict__ nT) {
  __shared__ float tile[64][65];
  const int jb = blockIdx.x & 15;
  const int cb = blockIdx.x >> 4;
  const int t  = threadIdx.x;
  const int r  = t >> 4;
  const int q  = t & 15;
#pragma unroll
  for (int i = 0; i < 4; ++i) {
    int row = r + i * 16;
    f32x4 v = *(const f32x4*)(nrm + (size_t)(cb * 64 + row) * Cc + jb * 64 + q * 4);
#pragma unroll
    for (int s = 0; s < 4; ++s) tile[row][q * 4 + s] = v[s];
  }
  __syncthreads();
#pragma unroll
  for (int i = 0; i < 4; ++i) {
    int j = r + i * 16;
    u16x4 hs;
#pragma unroll
    for (int s = 0; s < 4; ++s) hs[s] = f2bf(tile[q * 4 + s][j]);
    *(u16x4*)(nT + (size_t)(jb * 64 + j) * Cc + cb * 64 + q * 4) = hs;
  }
}

// ---------------------------------------------------------------------------
// Split kernel 1 (kexp): P[mb*128+r][colb*128+j] = exp(-g*sqd) as bf16.
// Per block: out tile 128x128; 4 waves, wave quadrant 64x64 (cr[4][4]).
// x staged f32->bf16 into LDS; cenb tile via async global_load_lds.
// ---------------------------------------------------------------------------
__global__ __launch_bounds__(256, 4) void kexp(
    const float* __restrict__ x, const float* __restrict__ gam,
    const uint16_t* __restrict__ cenb, const float* __restrict__ c2g,
    uint16_t* __restrict__ P, int row0) {
  extern __shared__ char smem[];
  char*  xB  = smem;                       // [128][128] bf16 linear
  char*  cB  = smem + 32768;               // [128][128] bf16 linear
  float* x2s = (float*)(smem + 65536);     // [128]

  const int tid  = threadIdx.x;
  const int lane = tid & 63;
  const int wid  = tid >> 6;
  const int wr   = wid >> 1;  // 0..1
  const int wc   = wid & 1;   // 0..1
  const int l15  = lane & 15;
  const int l4   = lane >> 4;
  const int colb = blockIdx.x & 7;         // 8 col-panels -> 8 XCDs
  const int mb   = blockIdx.x >> 3;

  // issue cenb tile async first (overlaps the x conversion below)
#pragma unroll
  for (int it = 0; it < 8; ++it) {
    int ch = tid + it * 256;               // 2048 chunks of 16B
    int r  = ch >> 4;
    int cc = ch & 15;
    gload16(cenb + (size_t)(colb * 128 + r) * Dk + cc * 8, cB + ch * 16);
  }
  // stage x tile (f32 -> bf16) + x2 row sums
#pragma unroll
  for (int it = 0; it < 8; ++it) {
    int ch = tid + it * 256;
    int r  = ch >> 4;
    int cc = ch & 15;
    const float* src = x + (size_t)(row0 + mb * 128 + r) * Dk + cc * 8;
    f32x4 v0 = __builtin_nontemporal_load((const f32x4*)src);
    f32x4 v1 = __builtin_nontemporal_load((const f32x4*)(src + 4));
    u16x8 hh;
    float ss = 0.f;
#pragma unroll
    for (int i = 0; i < 4; ++i) {
      hh[i]     = f2bf(v0[i]); ss += v0[i] * v0[i];
      hh[i + 4] = f2bf(v1[i]); ss += v1[i] * v1[i];
    }
    *(u16x8*)(xB + ch * 16) = hh;
    ss += __shfl_xor(ss, 1);
    ss += __shfl_xor(ss, 2);
    ss += __shfl_xor(ss, 4);
    ss += __shfl_xor(ss, 8);
    if ((tid & 15) == 0) x2s[r] = ss;
  }
  __syncthreads();

  f32x4 zero4 = {0.f, 0.f, 0.f, 0.f};
  f32x4 cr[4][4];
#pragma unroll
  for (int m = 0; m < 4; ++m)
#pragma unroll
    for (int n = 0; n < 4; ++n) cr[m][n] = zero4;

#pragma unroll
  for (int kk = 0; kk < 4; ++kk) {
    bf16x8 a[4], b[4];
#pragma unroll
    for (int m = 0; m < 4; ++m)
      a[m] = *(const bf16x8*)(xB + (64 * wr + 16 * m + l15) * 256 + kk * 64 + l4 * 16);
#pragma unroll
    for (int n = 0; n < 4; ++n)
      b[n] = *(const bf16x8*)(cB + (64 * wc + 16 * n + l15) * 256 + kk * 64 + l4 * 16);
#pragma unroll
    for (int m = 0; m < 4; ++m)
#pragma unroll
      for (int n = 0; n < 4; ++n) cr[m][n] = mfma_bf16(a[m], b[n], cr[m][n]);
  }

  // exp + bounce to LDS (reuse xB region) -> coalesced bf16 stores
  const float ngam = -gam[0];
  float c2v[4];
#pragma unroll
  for (int n = 0; n < 4; ++n) c2v[n] = c2g[colb * 128 + 64 * wc + 16 * n + l15];
  __syncthreads();  // all LDS MFMA reads done
  uint16_t* pbuf = (uint16_t*)smem;  // [128][128]
#pragma unroll
  for (int m = 0; m < 4; ++m) {
#pragma unroll
    for (int n = 0; n < 4; ++n) {
#pragma unroll
      for (int r = 0; r < 4; ++r) {
        int row = 64 * wr + 16 * m + l4 * 4 + r;
        float s = fmaxf(fmaf(-2.f, cr[m][n][r], x2s[row] + c2v[n]), 0.f);
        float p = __expf(ngam * s);
        pbuf[row * 128 + 64 * wc + 16 * n + l15] = f2bf(p);
      }
    }
  }
  __syncthreads();
#pragma unroll
  for (int it = 0; it < 8; ++it) {
    int ch = tid + it * 256;   // 2048 chunks of 16B
    int r  = ch >> 4;
    int cc = ch & 15;
    *(u16x8*)(P + (size_t)(mb * 128 + r) * Cc + colb * 128 + cc * 8) =
        *(const u16x8*)((const char*)pbuf + ch * 16);
  }
}

// ---------------------------------------------------------------------------
// Split kernel 2 (g2): out = P @ nT^T  (both bf16, K=1024), m97-style:
// 128x128 tile, BK=64, 4 waves, async global_load_lds staging, 2-barrier loop.
// nb = blockIdx%8 -> XCD: each XCD's L2 keeps one 256 KB nT panel resident.
// ---------------------------------------------------------------------------
__global__ __launch_bounds__(256, 4) void g2(
    const uint16_t* __restrict__ P, const uint16_t* __restrict__ nT,
    float* __restrict__ out, int row0) {
  extern __shared__ char smem[];
  char* aB = smem;            // [128][64] bf16 linear
  char* bB = smem + 16384;    // [128][64] bf16 linear

  const int tid  = threadIdx.x;
  const int lane = tid & 63;
  const int wid  = tid >> 6;
  const int wr   = wid >> 1;
  const int wc   = wid & 1;
  const int l15  = lane & 15;
  const int l4   = lane >> 4;
  const int nb   = blockIdx.x & 7;
  const int mb   = blockIdx.x >> 3;

  const uint16_t* Pbase = P + (size_t)(mb * 128) * Cc;
  const uint16_t* Nbase = nT + (size_t)(nb * 128) * Cc;

  f32x4 zero4 = {0.f, 0.f, 0.f, 0.f};
  f32x4 acc[4][4];
#pragma unroll
  for (int m = 0; m < 4; ++m)
#pragma unroll
    for (int n = 0; n < 4; ++n) acc[m][n] = zero4;

  for (int k0 = 0; k0 < Cc; k0 += 64) {
#pragma unroll
    for (int i = 0; i < 4; ++i) {
      int ch = tid + i * 256;          // 1024 chunks of 16B (A tile)
      int r  = ch >> 3;
      int c8 = ch & 7;
      gload16(Pbase + (size_t)r * Cc + k0 + c8 * 8, aB + ch * 16);
    }
#pragma unroll
    for (int i = 0; i < 4; ++i) {
      int ch = tid + i * 256;          // 1024 chunks of 16B (B tile)
      int r  = ch >> 3;
      int c8 = ch & 7;
      gload16(Nbase + (size_t)r * Cc + k0 + c8 * 8, bB + ch * 16);
    }
    __syncthreads();                   // vmcnt(0) drained by compiler
#pragma unroll
    for (int kk = 0; kk < 2; ++kk) {
      bf16x8 a[4], b[4];
#pragma unroll
      for (int m = 0; m < 4; ++m)
        a[m] = *(const bf16x8*)(aB + (64 * wr + 16 * m + l15) * 128 + kk * 64 + l4 * 16);
#pragma unroll
      for (int n = 0; n < 4; ++n)
        b[n] = *(const bf16x8*)(bB + (64 * wc + 16 * n + l15) * 128 + kk * 64 + l4 * 16);
#pragma unroll
      for (int m = 0; m < 4; ++m)
#pragma unroll
        for (int n = 0; n < 4; ++n) acc[m][n] = mfma_bf16(a[m], b[n], acc[m][n]);
    }
    __syncthreads();
  }

  // epilogue: LDS bounce ([64][128] f32 = 32 KB), halves by wr
  float* buf = (float*)smem;
  const size_t orow = (size_t)row0 + mb * 128;
#pragma unroll
  for (int h = 0; h < 2; ++h) {
    __syncthreads();
    if (wr == h) {
#pragma unroll
      for (int m = 0; m < 4; ++m)
#pragma unroll
        for (int n = 0; n < 4; ++n)
#pragma unroll
          for (int r = 0; r < 4; ++r)
            buf[(16 * m + l4 * 4 + r) * 128 + 64 * wc + 16 * n + l15] = acc[m][n][r];
    }
    __syncthreads();
#pragma unroll
    for (int i = 0; i < 8; ++i) {
      int ch = tid + i * 256;          // 2048 chunks of 16B
      int rL = ch >> 5;
      int c4 = ch & 31;
      *(f32x4*)(out + (orow + 64 * h + rL) * Cc + nb * 128 + c4 * 4) =
          *(const f32x4*)(buf + rL * 128 + c4 * 4);
    }
  }
}

// ---------------------------------------------------------------------------
// Fused fallback (R5, best known when ws is small) — unchanged.
// ---------------------------------------------------------------------------
template <int USE_NT>
__global__ __launch_bounds__(512, 4) void nyst_main(
    const float* __restrict__ x, const float* __restrict__ cen,
    const float* __restrict__ gam, const float* __restrict__ nrm,
    const uint16_t* __restrict__ cenb, const float* __restrict__ c2g,
    const uint16_t* __restrict__ nT, float* __restrict__ out) {
  extern __shared__ char smem[];
  char*  xB  = smem;
  char*  pB  = smem + XBYTES;
  float* x2s = (float*)(smem + XBYTES + PBYTES);
  float* c2s = (float*)(smem + LDS_MAIN);

  const int tid  = threadIdx.x;
  const int lane = tid & 63;
  const int wid  = tid >> 6;
  const int wr   = wid >> 2;
  const int wc   = wid & 3;
  const int xcd  = blockIdx.x & 7;
  const int bi   = blockIdx.x >> 3;
  const int colb = xcd >> 1;
  const int rowb = (bi << 1) | (xcd & 1);
  const int l15  = lane & 15;
  const int l4   = lane >> 4;

  const float* xblk = x + (size_t)rowb * BM * Dk;

#pragma unroll
  for (int it = 0; it < 2; ++it) {
    int ch = tid + it * 512;
    int r  = ch >> 4;
    int cc = ch & 15;
    const float* src = xblk + r * Dk + cc * 8;
    f32x4 v0 = __builtin_nontemporal_load((const f32x4*)src);
    f32x4 v1 = __builtin_nontemporal_load((const f32x4*)(src + 4));
    u16x8 hh;
    float ss = 0.f;
#pragma unroll
    for (int i = 0; i < 4; ++i) {
      hh[i]     = f2bf(v0[i]); ss += v0[i] * v0[i];
      hh[i + 4] = f2bf(v1[i]); ss += v1[i] * v1[i];
    }
    int off = (r * 256 + cc * 16) ^ ((r & 7) << 4);
    *(u16x8*)(xB + off) = hh;
    ss += __shfl_xor(ss, 1);
    ss += __shfl_xor(ss, 2);
    ss += __shfl_xor(ss, 4);
    ss += __shfl_xor(ss, 8);
    if ((tid & 15) == 0) x2s[r] = ss;
  }
  if (!USE_NT) {
#pragma unroll
    for (int rr = 0; rr < 2; ++rr) {
      int r = tid + rr * 512;
      const float* src = cen + (size_t)r * Dk;
      float ss = 0.f;
      for (int k = 0; k < Dk / 4; ++k) {
        f32x4 v = *(const f32x4*)(src + 4 * k);
        ss += v[0] * v[0] + v[1] * v[1] + v[2] * v[2] + v[3] * v[3];
      }
      c2s[r] = ss;
    }
  }
  __syncthreads();

  const float ngam = -gam[0];
  f32x4 zero4 = {0.f, 0.f, 0.f, 0.f};
  f32x4 acc[2][4];
#pragma unroll
  for (int m = 0; m < 2; ++m)
#pragma unroll
    for (int n = 0; n < 4; ++n) acc[m][n] = zero4;

  for (int c0 = 0; c0 < Cc; c0 += KB) {
    f32x4 cr[2][2];
#pragma unroll
    for (int g = 0; g < 2; ++g)
#pragma unroll
      for (int m = 0; m < 2; ++m) cr[g][m] = zero4;

#pragma unroll
    for (int kk = 0; kk < 4; ++kk) {
      bf16x8 b0, b1;
      if (USE_NT) {
        int c0col = c0 + 16 * wc + l15;
        b0 = *(const bf16x8*)(cenb + (size_t)c0col * Dk + kk * 32 + l4 * 8);
        b1 = *(const bf16x8*)(cenb + (size_t)(c0col + 64) * Dk + kk * 32 + l4 * 8);
      } else {
#pragma unroll
        for (int g = 0; g < 2; ++g) {
          int ccol = c0 + g * 64 + 16 * wc + l15;
          const float* cb_ = cen + (size_t)ccol * Dk + kk * 32 + l4 * 8;
          f32x4 v0 = *(const f32x4*)cb_;
          f32x4 v1 = *(const f32x4*)(cb_ + 4);
          u16x8 tt;
#pragma unroll
          for (int i = 0; i < 4; ++i) { tt[i] = f2bf(v0[i]); tt[i + 4] = f2bf(v1[i]); }
          if (g == 0) b0 = __builtin_bit_cast(bf16x8, tt);
          else        b1 = __builtin_bit_cast(bf16x8, tt);
        }
      }
#pragma unroll
      for (int m = 0; m < 2; ++m) {
        int row = 32 * wr + 16 * m + l15;
        int off = (row * 256 + kk * 64 + l4 * 16) ^ ((row & 7) << 4);
        bf16x8 a = *(const bf16x8*)(xB + off);
        cr[0][m] = mfma_bf16(a, b0, cr[0][m]);
        cr[1][m] = mfma_bf16(a, b1, cr[1][m]);
      }
    }

    __syncthreads();
#pragma unroll
    for (int g = 0; g < 2; ++g) {
      int ccol = c0 + g * 64 + 16 * wc + l15;
      float c2v = USE_NT ? c2g[ccol] : c2s[ccol];
#pragma unroll
      for (int m = 0; m < 2; ++m) {
#pragma unroll
        for (int r = 0; r < 4; ++r) {
          int row = 32 * wr + 16 * m + l4 * 4 + r;
          float s = fmaxf(fmaf(-2.f, cr[g][m][r], x2s[row] + c2v), 0.f);
          float p = __expf(ngam * s);
          int off = (row * 256 + (g * 64 + 16 * wc + l15) * 2) ^ ((row & 7) << 4);
          *(uint16_t*)(pB + off) = f2bf(p);
        }
      }
    }
    __syncthreads();

#pragma unroll
    for (int kk = 0; kk < 4; ++kk) {
      bf16x8 pa[2];
#pragma unroll
      for (int m = 0; m < 2; ++m) {
        int row = 32 * wr + 16 * m + l15;
        int off = (row * 256 + kk * 64 + l4 * 16) ^ ((row & 7) << 4);
        pa[m] = *(const bf16x8*)(pB + off);
      }
      int krow = c0 + kk * 32 + l4 * 8;
#pragma unroll
      for (int n = 0; n < 4; ++n) {
        int j = colb * BN + wc * 64 + 16 * n + l15;
        bf16x8 bm;
        if (USE_NT) {
          bm = *(const bf16x8*)(nT + (size_t)j * Cc + krow);
        } else {
          u16x8 tt;
#pragma unroll
          for (int i = 0; i < 8; ++i) tt[i] = f2bf(nrm[(size_t)(krow + i) * Cc + j]);
          bm = __builtin_bit_cast(bf16x8, tt);
        }
        acc[0][n] = mfma_bf16(pa[0], bm, acc[0][n]);
        acc[1][n] = mfma_bf16(pa[1], bm, acc[1][n]);
      }
    }
  }

  float* outBuf = (float*)smem;
  const int orow0 = rowb * BM;
#pragma unroll
  for (int h = 0; h < 2; ++h) {
    __syncthreads();
    if (wr == h) {
#pragma unroll
      for (int m = 0; m < 2; ++m) {
#pragma unroll
        for (int n = 0; n < 4; ++n) {
#pragma unroll
          for (int r = 0; r < 4; ++r) {
            int rL = 16 * m + l4 * 4 + r;
            outBuf[rL * 256 + wc * 64 + 16 * n + l15] = acc[m][n][r];
          }
        }
      }
    }
    __syncthreads();
#pragma unroll
    for (int i = 0; i < 4; ++i) {
      int ch = tid + 512 * i;
      int rL = ch >> 6;
      int c4 = ch & 63;
      f32x4 v = *(const f32x4*)(outBuf + rL * 256 + c4 * 4);
      *(f32x4*)(out + (size_t)(orow0 + 32 * h + rL) * Cc + colb * BN + c4 * 4) = v;
    }
  }
}

// ---------------------------------------------------------------------------
extern "C" void kernel_launch(void* const* d_in, const int* in_sizes, int n_in,
                              void* d_out, int out_size, void* d_ws, size_t ws_size,
                              hipStream_t stream) {
  const float* x   = (const float*)d_in[0];  // [131072,128]
  const float* cen = (const float*)d_in[1];  // [1024,128]
  const float* gam = (const float*)d_in[2];  // [1]
  const float* nrm = (const float*)d_in[3];  // [1024,1024]
  float* out = (float*)d_out;

  const size_t cenbB = (size_t)Cc * Dk * 2;            // 256 KB
  const size_t c2B   = (size_t)Cc * 4;                 // 4 KB
  const size_t nTB   = (size_t)Cc * Cc * 2;            // 2 MB
  const size_t pChB  = (size_t)CH * Cc * 2;            // 33.5 MB

  if (ws_size >= cenbB + c2B + nTB + pChB) {
    // -------- split path: prep -> per-chunk { kexp -> g2 } --------
    uint16_t* cenb = (uint16_t*)d_ws;
    float*    c2   = (float*)((char*)d_ws + cenbB);
    uint16_t* nT   = (uint16_t*)((char*)d_ws + cenbB + c2B);
    uint16_t* Pws  = (uint16_t*)((char*)d_ws + cenbB + c2B + nTB);
    prep_cen<<<64, 256, 0, stream>>>(cen, cenb, c2);
    prep_nT<<<256, 256, 0, stream>>>(nrm, nT);
    const int gridC = (CH / 128) * 8;  // 1024
    for (int c = 0; c < NCHUNK; ++c) {
      kexp<<<gridC, 256, 66048, stream>>>(x, gam, cenb, c2, Pws, c * CH);
      g2<<<gridC, 256, 32768, stream>>>(Pws, nT, out, c * CH);
    }
  } else if (ws_size >= cenbB + c2B + nTB) {
    uint16_t* cenb = (uint16_t*)d_ws;
    float*    c2   = (float*)((char*)d_ws + cenbB);
    uint16_t* nT   = (uint16_t*)((char*)d_ws + cenbB + c2B);
    prep_cen<<<64, 256, 0, stream>>>(cen, cenb, c2);
    prep_nT<<<256, 256, 0, stream>>>(nrm, nT);
    nyst_main<1><<<(Nrows / BM) * NCB, 512, LDS_MAIN, stream>>>(
        x, cen, gam, nrm, cenb, c2, nT, out);
  } else {
    nyst_main<0><<<(Nrows / BM) * NCB, 512, LDS_FB, stream>>>(
        x, cen, gam, nrm, nullptr, nullptr, nullptr, out);
  }
}

// Round 8
// 552.538 us; speedup vs baseline: 4.3414x; 1.2811x over previous
//
#include <hip/hip_runtime.h>
#include <stdint.h>

typedef float    f32x4  __attribute__((ext_vector_type(4)));
typedef __bf16   bf16x8 __attribute__((ext_vector_type(8)));
typedef uint16_t u16x8  __attribute__((ext_vector_type(8)));
typedef uint16_t u16x4  __attribute__((ext_vector_type(4)));

static __device__ __forceinline__ f32x4 mfma_bf16(bf16x8 a, bf16x8 b, f32x4 c) {
  return __builtin_amdgcn_mfma_f32_16x16x32_bf16(a, b, c, 0, 0, 0);
}
// fp32 -> bf16 round-to-nearest-even
static __device__ __forceinline__ uint16_t f2bf(float f) {
  uint32_t u = __builtin_bit_cast(uint32_t, f);
  u += 0x7fffu + ((u >> 16) & 1u);
  return (uint16_t)(u >> 16);
}
// async global->LDS, 16B per lane (gfx950). dest must be linear-in-lane.
static __device__ __forceinline__ void gload16(const void* src, void* lds) {
  __builtin_amdgcn_global_load_lds(
      (const __attribute__((address_space(1))) void*)src,
      (__attribute__((address_space(3))) void*)lds, 16, 0, 0);
}

constexpr int Nrows = 131072;
constexpr int Dk    = 128;
constexpr int Cc    = 1024;
constexpr int CH     = 16384;          // rows per chunk (mid-ws fallback)
constexpr int NCHUNK = Nrows / CH;     // 8
// fused fallback (R5) geometry
constexpr int BMf   = 64;
constexpr int BNf   = 256;
constexpr int KBf   = 128;
constexpr int XBYTES = BMf * Dk * 2;
constexpr int PBYTES = BMf * KBf * 2;
constexpr int LDS_MAIN = XBYTES + PBYTES + BMf * 4;
constexpr int LDS_FB   = LDS_MAIN + Cc * 4;

// ---------------------------------------------------------------------------
// Prep A: centers -> bf16 [C][D], and c2[C]
// ---------------------------------------------------------------------------
__global__ void prep_cen(const float* __restrict__ cen,
                         uint16_t* __restrict__ cenb,
                         float* __restrict__ c2) {
  const int t = threadIdx.x;
  const int row = blockIdx.x * 16 + (t >> 4);
  const int q = t & 15;
  const float* src = cen + (size_t)row * Dk + q * 8;
  f32x4 v0 = *(const f32x4*)src;
  f32x4 v1 = *(const f32x4*)(src + 4);
  u16x8 h;
  float ss = 0.f;
#pragma unroll
  for (int i = 0; i < 4; ++i) {
    h[i]     = f2bf(v0[i]); ss += v0[i] * v0[i];
    h[i + 4] = f2bf(v1[i]); ss += v1[i] * v1[i];
  }
  *(u16x8*)(cenb + (size_t)row * Dk + q * 8) = h;
  ss += __shfl_xor(ss, 1);
  ss += __shfl_xor(ss, 2);
  ss += __shfl_xor(ss, 4);
  ss += __shfl_xor(ss, 8);
  if (q == 0) c2[row] = ss;
}

// ---------------------------------------------------------------------------
// Prep B: nT[j][c] = bf16(norm[c][j])
// ---------------------------------------------------------------------------
__global__ void prep_nT(const float* __restrict__ nrm, uint16_t* __restrict__ nT) {
  __shared__ float tile[64][65];
  const int jb = blockIdx.x & 15;
  const int cb = blockIdx.x >> 4;
  const int t  = threadIdx.x;
  const int r  = t >> 4;
  const int q  = t & 15;
#pragma unroll
  for (int i = 0; i < 4; ++i) {
    int row = r + i * 16;
    f32x4 v = *(const f32x4*)(nrm + (size_t)(cb * 64 + row) * Cc + jb * 64 + q * 4);
#pragma unroll
    for (int s = 0; s < 4; ++s) tile[row][q * 4 + s] = v[s];
  }
  __syncthreads();
#pragma unroll
  for (int i = 0; i < 4; ++i) {
    int j = r + i * 16;
    u16x4 hs;
#pragma unroll
    for (int s = 0; s < 4; ++s) hs[s] = f2bf(tile[q * 4 + s][j]);
    *(u16x4*)(nT + (size_t)(jb * 64 + j) * Cc + cb * 64 + q * 4) = hs;
  }
}

// ---------------------------------------------------------------------------
// kexp: P[mb*128+r][colb*128+j] = bf16(exp(-g*sqd)). (proven in R7)
// ---------------------------------------------------------------------------
__global__ __launch_bounds__(256, 4) void kexp(
    const float* __restrict__ x, const float* __restrict__ gam,
    const uint16_t* __restrict__ cenb, const float* __restrict__ c2g,
    uint16_t* __restrict__ P, int row0) {
  extern __shared__ char smem[];
  char*  xB  = smem;                       // [128][128] bf16 linear
  char*  cB  = smem + 32768;               // [128][128] bf16 linear
  float* x2s = (float*)(smem + 65536);     // [128]

  const int tid  = threadIdx.x;
  const int lane = tid & 63;
  const int wid  = tid >> 6;
  const int wr   = wid >> 1;
  const int wc   = wid & 1;
  const int l15  = lane & 15;
  const int l4   = lane >> 4;
  const int colb = blockIdx.x & 7;
  const int mb   = blockIdx.x >> 3;

#pragma unroll
  for (int it = 0; it < 8; ++it) {
    int ch = tid + it * 256;
    int r  = ch >> 4;
    int cc = ch & 15;
    gload16(cenb + (size_t)(colb * 128 + r) * Dk + cc * 8, cB + ch * 16);
  }
#pragma unroll
  for (int it = 0; it < 8; ++it) {
    int ch = tid + it * 256;
    int r  = ch >> 4;
    int cc = ch & 15;
    const float* src = x + (size_t)(row0 + mb * 128 + r) * Dk + cc * 8;
    f32x4 v0 = __builtin_nontemporal_load((const f32x4*)src);
    f32x4 v1 = __builtin_nontemporal_load((const f32x4*)(src + 4));
    u16x8 hh;
    float ss = 0.f;
#pragma unroll
    for (int i = 0; i < 4; ++i) {
      hh[i]     = f2bf(v0[i]); ss += v0[i] * v0[i];
      hh[i + 4] = f2bf(v1[i]); ss += v1[i] * v1[i];
    }
    *(u16x8*)(xB + ch * 16) = hh;
    ss += __shfl_xor(ss, 1);
    ss += __shfl_xor(ss, 2);
    ss += __shfl_xor(ss, 4);
    ss += __shfl_xor(ss, 8);
    if ((tid & 15) == 0) x2s[r] = ss;
  }
  __syncthreads();

  f32x4 zero4 = {0.f, 0.f, 0.f, 0.f};
  f32x4 cr[4][4];
#pragma unroll
  for (int m = 0; m < 4; ++m)
#pragma unroll
    for (int n = 0; n < 4; ++n) cr[m][n] = zero4;

#pragma unroll
  for (int kk = 0; kk < 4; ++kk) {
    bf16x8 a[4], b[4];
#pragma unroll
    for (int m = 0; m < 4; ++m)
      a[m] = *(const bf16x8*)(xB + (64 * wr + 16 * m + l15) * 256 + kk * 64 + l4 * 16);
#pragma unroll
    for (int n = 0; n < 4; ++n)
      b[n] = *(const bf16x8*)(cB + (64 * wc + 16 * n + l15) * 256 + kk * 64 + l4 * 16);
#pragma unroll
    for (int m = 0; m < 4; ++m)
#pragma unroll
      for (int n = 0; n < 4; ++n) cr[m][n] = mfma_bf16(a[m], b[n], cr[m][n]);
  }

  const float ngam = -gam[0];
  float c2v[4];
#pragma unroll
  for (int n = 0; n < 4; ++n) c2v[n] = c2g[colb * 128 + 64 * wc + 16 * n + l15];
  __syncthreads();
  uint16_t* pbuf = (uint16_t*)smem;
#pragma unroll
  for (int m = 0; m < 4; ++m) {
#pragma unroll
    for (int n = 0; n < 4; ++n) {
#pragma unroll
      for (int r = 0; r < 4; ++r) {
        int row = 64 * wr + 16 * m + l4 * 4 + r;
        float s = fmaxf(fmaf(-2.f, cr[m][n][r], x2s[row] + c2v[n]), 0.f);
        float p = __expf(ngam * s);
        pbuf[row * 128 + 64 * wc + 16 * n + l15] = f2bf(p);
      }
    }
  }
  __syncthreads();
#pragma unroll
  for (int it = 0; it < 8; ++it) {
    int ch = tid + it * 256;
    int r  = ch >> 4;
    int cc = ch & 15;
    *(u16x8*)(P + (size_t)(mb * 128 + r) * Cc + colb * 128 + cc * 8) =
        *(const u16x8*)((const char*)pbuf + ch * 16);
  }
}

// ---------------------------------------------------------------------------
// g2_8p: out = P @ nT^T, 256x256 tile, BK=64, 8 waves (2Mx4N), 128 KB LDS
// double-buffer. 8-phase schedule per 2 K-tiles: each phase issues one
// half-tile stage (2 x gload_lds), counted vmcnt(2) ONCE per K-tile (drain
// only at the peeled last tile), raw s_barrier pairs, setprio'd 16-MFMA
// bursts. T2 swizzle: linear LDS dest + inverse-swizzled GLOBAL source +
// XOR-swizzled ds_read (byte ^ ((row&7)<<4)) -- both-sides rule.
// ---------------------------------------------------------------------------
__global__ __launch_bounds__(512, 2) void g2_8p(
    const uint16_t* __restrict__ P, const uint16_t* __restrict__ nT,
    float* __restrict__ out, int row0, int mblocks) {
  extern __shared__ char smem[];
  char* a0 = smem;
  char* b0 = smem + 32768;
  char* a1 = smem + 65536;
  char* b1 = smem + 98304;

  const int tid  = threadIdx.x;
  const int lane = tid & 63;
  const int wid  = tid >> 6;      // 0..7
  const int wm   = wid >> 2;      // 0..1
  const int wn   = wid & 3;       // 0..3
  const int l15  = lane & 15;
  const int l4   = lane >> 4;

  // bijective XCD swizzle (nwg % 8 == 0): XCD k owns a contiguous wgid chunk
  // with nb fastest -> full nT (2 MB) L2-resident per XCD, A tiles reused 4x.
  const int nwg  = mblocks * 4;
  const int cpx  = nwg >> 3;
  const int wgid = (blockIdx.x & 7) * cpx + (blockIdx.x >> 3);
  const int nb   = wgid & 3;
  const int mb   = wgid >> 2;

  const uint16_t* Abase = P + (size_t)mb * 256 * Cc;
  const uint16_t* Bbase = nT + (size_t)nb * 256 * Cc;

  f32x4 acc[8][4];
#pragma unroll
  for (int m = 0; m < 8; ++m)
#pragma unroll
    for (int n = 0; n < 4; ++n) acc[m][n] = f32x4{0.f, 0.f, 0.f, 0.f};

  // stage one half-tile (1024 chunks of 16B; 2 per thread), source-swizzled
  auto stage_half = [&](const uint16_t* gb, char* db, int k0, int h) {
    int ch0 = h * 1024 + tid;
    int ch1 = ch0 + 512;
    int r0 = ch0 >> 3, r1 = ch1 >> 3;
    gload16(gb + (size_t)r0 * Cc + k0 + ((ch0 & 7) ^ (r0 & 7)) * 8, db + ch0 * 16);
    gload16(gb + (size_t)r1 * Cc + k0 + ((ch1 & 7) ^ (r1 & 7)) * 8, db + ch1 * 16);
  };

  // prologue: stage K-tile 0 fully into buf0 (8 loads/thread in flight)
  stage_half(Abase, a0, 0, 0);
  stage_half(Abase, a0, 0, 1);
  stage_half(Bbase, b0, 0, 0);
  stage_half(Bbase, b0, 0, 1);

  for (int kt = 0; kt < 16; ++kt) {
    char* aC = (kt & 1) ? a1 : a0;
    char* bC = (kt & 1) ? b1 : b0;
    char* aN = (kt & 1) ? a0 : a1;
    char* bN = (kt & 1) ? b0 : b1;
    const int k1 = (kt + 1) * 64;
    const bool st = (kt < 15);

    bf16x8 bF[4][2];  // B frags for this K-tile, live across the 4 phases

#pragma unroll
    for (int p = 0; p < 4; ++p) {
      // --- issue this phase's half-tile prefetch (into the freed buffer) ---
      if (st) {
        const uint16_t* gb = (p < 2) ? Abase : Bbase;
        char* db = (p < 2) ? aN : bN;
        stage_half(gb, db, k1, p & 1);
      }
      if (p == 0) {
        // validate K-tile kt: all loads except the 2 just issued have landed
        if (kt == 15) asm volatile("s_waitcnt vmcnt(0)" ::: "memory");
        else          asm volatile("s_waitcnt vmcnt(2)" ::: "memory");
      }
      __builtin_amdgcn_s_barrier();

      if (p == 0) {
#pragma unroll
        for (int n = 0; n < 4; ++n)
#pragma unroll
          for (int kk = 0; kk < 2; ++kk) {
            int row = wn * 64 + n * 16 + l15;
            bF[n][kk] = *(const bf16x8*)(bC + row * 128 +
                                         (((kk * 4 + l4) ^ (row & 7)) * 16));
          }
      }
      bf16x8 aF[2][2];
#pragma unroll
      for (int mm = 0; mm < 2; ++mm)
#pragma unroll
        for (int kk = 0; kk < 2; ++kk) {
          int row = wm * 128 + (2 * p + mm) * 16 + l15;
          aF[mm][kk] = *(const bf16x8*)(aC + row * 128 +
                                        (((kk * 4 + l4) ^ (row & 7)) * 16));
        }
      __builtin_amdgcn_s_setprio(1);
#pragma unroll
      for (int mm = 0; mm < 2; ++mm)
#pragma unroll
        for (int n = 0; n < 4; ++n)
#pragma unroll
          for (int kk = 0; kk < 2; ++kk)
            acc[2 * p + mm][n] = mfma_bf16(aF[mm][kk], bF[n][kk], acc[2 * p + mm][n]);
      __builtin_amdgcn_s_setprio(0);
      __builtin_amdgcn_s_barrier();
    }
  }

  // epilogue: bounce halves (128 rows x 256 f32 = 128 KB) -> coalesced stores
  float* obuf = (float*)smem;
#pragma unroll
  for (int h = 0; h < 2; ++h) {
    __syncthreads();
    if (wm == h) {
#pragma unroll
      for (int m = 0; m < 8; ++m)
#pragma unroll
        for (int n = 0; n < 4; ++n)
#pragma unroll
          for (int r = 0; r < 4; ++r) {
            int rL = m * 16 + l4 * 4 + r;  // 0..127
            obuf[rL * 256 + wn * 64 + 16 * n + l15] = acc[m][n][r];
          }
    }
    __syncthreads();
#pragma unroll
    for (int i = 0; i < 16; ++i) {
      int ch = tid + i * 512;   // 8192 chunks of 16B
      int rL = ch >> 6;         // 0..127
      int c4 = ch & 63;
      *(f32x4*)(out + (size_t)(row0 + mb * 256 + h * 128 + rL) * Cc +
                nb * 256 + c4 * 4) = *(const f32x4*)(obuf + rL * 256 + c4 * 4);
    }
  }
}

// ---------------------------------------------------------------------------
// Fused fallback (R5) — only used when ws is too small for the split path.
// ---------------------------------------------------------------------------
template <int USE_NT>
__global__ __launch_bounds__(512, 4) void nyst_main(
    const float* __restrict__ x, const float* __restrict__ cen,
    const float* __restrict__ gam, const float* __restrict__ nrm,
    const uint16_t* __restrict__ cenb, const float* __restrict__ c2g,
    const uint16_t* __restrict__ nT, float* __restrict__ out) {
  extern __shared__ char smem[];
  char*  xB  = smem;
  char*  pB  = smem + XBYTES;
  float* x2s = (float*)(smem + XBYTES + PBYTES);
  float* c2s = (float*)(smem + LDS_MAIN);

  const int tid  = threadIdx.x;
  const int lane = tid & 63;
  const int wid  = tid >> 6;
  const int wr   = wid >> 2;
  const int wc   = wid & 3;
  const int xcd  = blockIdx.x & 7;
  const int bi   = blockIdx.x >> 3;
  const int colb = xcd >> 1;
  const int rowb = (bi << 1) | (xcd & 1);
  const int l15  = lane & 15;
  const int l4   = lane >> 4;

  const float* xblk = x + (size_t)rowb * BMf * Dk;

#pragma unroll
  for (int it = 0; it < 2; ++it) {
    int ch = tid + it * 512;
    int r  = ch >> 4;
    int cc = ch & 15;
    const float* src = xblk + r * Dk + cc * 8;
    f32x4 v0 = __builtin_nontemporal_load((const f32x4*)src);
    f32x4 v1 = __builtin_nontemporal_load((const f32x4*)(src + 4));
    u16x8 hh;
    float ss = 0.f;
#pragma unroll
    for (int i = 0; i < 4; ++i) {
      hh[i]     = f2bf(v0[i]); ss += v0[i] * v0[i];
      hh[i + 4] = f2bf(v1[i]); ss += v1[i] * v1[i];
    }
    int off = (r * 256 + cc * 16) ^ ((r & 7) << 4);
    *(u16x8*)(xB + off) = hh;
    ss += __shfl_xor(ss, 1);
    ss += __shfl_xor(ss, 2);
    ss += __shfl_xor(ss, 4);
    ss += __shfl_xor(ss, 8);
    if ((tid & 15) == 0) x2s[r] = ss;
  }
  if (!USE_NT) {
#pragma unroll
    for (int rr = 0; rr < 2; ++rr) {
      int r = tid + rr * 512;
      const float* src = cen + (size_t)r * Dk;
      float ss = 0.f;
      for (int k = 0; k < Dk / 4; ++k) {
        f32x4 v = *(const f32x4*)(src + 4 * k);
        ss += v[0] * v[0] + v[1] * v[1] + v[2] * v[2] + v[3] * v[3];
      }
      c2s[r] = ss;
    }
  }
  __syncthreads();

  const float ngam = -gam[0];
  f32x4 zero4 = {0.f, 0.f, 0.f, 0.f};
  f32x4 acc[2][4];
#pragma unroll
  for (int m = 0; m < 2; ++m)
#pragma unroll
    for (int n = 0; n < 4; ++n) acc[m][n] = zero4;

  for (int c0 = 0; c0 < Cc; c0 += KBf) {
    f32x4 cr[2][2];
#pragma unroll
    for (int g = 0; g < 2; ++g)
#pragma unroll
      for (int m = 0; m < 2; ++m) cr[g][m] = zero4;

#pragma unroll
    for (int kk = 0; kk < 4; ++kk) {
      bf16x8 b0, b1;
      if (USE_NT) {
        int c0col = c0 + 16 * wc + l15;
        b0 = *(const bf16x8*)(cenb + (size_t)c0col * Dk + kk * 32 + l4 * 8);
        b1 = *(const bf16x8*)(cenb + (size_t)(c0col + 64) * Dk + kk * 32 + l4 * 8);
      } else {
#pragma unroll
        for (int g = 0; g < 2; ++g) {
          int ccol = c0 + g * 64 + 16 * wc + l15;
          const float* cb_ = cen + (size_t)ccol * Dk + kk * 32 + l4 * 8;
          f32x4 v0 = *(const f32x4*)cb_;
          f32x4 v1 = *(const f32x4*)(cb_ + 4);
          u16x8 tt;
#pragma unroll
          for (int i = 0; i < 4; ++i) { tt[i] = f2bf(v0[i]); tt[i + 4] = f2bf(v1[i]); }
          if (g == 0) b0 = __builtin_bit_cast(bf16x8, tt);
          else        b1 = __builtin_bit_cast(bf16x8, tt);
        }
      }
#pragma unroll
      for (int m = 0; m < 2; ++m) {
        int row = 32 * wr + 16 * m + l15;
        int off = (row * 256 + kk * 64 + l4 * 16) ^ ((row & 7) << 4);
        bf16x8 a = *(const bf16x8*)(xB + off);
        cr[0][m] = mfma_bf16(a, b0, cr[0][m]);
        cr[1][m] = mfma_bf16(a, b1, cr[1][m]);
      }
    }

    __syncthreads();
#pragma unroll
    for (int g = 0; g < 2; ++g) {
      int ccol = c0 + g * 64 + 16 * wc + l15;
      float c2v = USE_NT ? c2g[ccol] : c2s[ccol];
#pragma unroll
      for (int m = 0; m < 2; ++m) {
#pragma unroll
        for (int r = 0; r < 4; ++r) {
          int row = 32 * wr + 16 * m + l4 * 4 + r;
          float s = fmaxf(fmaf(-2.f, cr[g][m][r], x2s[row] + c2v), 0.f);
          float p = __expf(ngam * s);
          int off = (row * 256 + (g * 64 + 16 * wc + l15) * 2) ^ ((row & 7) << 4);
          *(uint16_t*)(pB + off) = f2bf(p);
        }
      }
    }
    __syncthreads();

#pragma unroll
    for (int kk = 0; kk < 4; ++kk) {
      bf16x8 pa[2];
#pragma unroll
      for (int m = 0; m < 2; ++m) {
        int row = 32 * wr + 16 * m + l15;
        int off = (row * 256 + kk * 64 + l4 * 16) ^ ((row & 7) << 4);
        pa[m] = *(const bf16x8*)(pB + off);
      }
      int krow = c0 + kk * 32 + l4 * 8;
#pragma unroll
      for (int n = 0; n < 4; ++n) {
        int j = colb * BNf + wc * 64 + 16 * n + l15;
        bf16x8 bm;
        if (USE_NT) {
          bm = *(const bf16x8*)(nT + (size_t)j * Cc + krow);
        } else {
          u16x8 tt;
#pragma unroll
          for (int i = 0; i < 8; ++i) tt[i] = f2bf(nrm[(size_t)(krow + i) * Cc + j]);
          bm = __builtin_bit_cast(bf16x8, tt);
        }
        acc[0][n] = mfma_bf16(pa[0], bm, acc[0][n]);
        acc[1][n] = mfma_bf16(pa[1], bm, acc[1][n]);
      }
    }
  }

  float* outBuf = (float*)smem;
  const int orow0 = rowb * BMf;
#pragma unroll
  for (int h = 0; h < 2; ++h) {
    __syncthreads();
    if (wr == h) {
#pragma unroll
      for (int m = 0; m < 2; ++m) {
#pragma unroll
        for (int n = 0; n < 4; ++n) {
#pragma unroll
          for (int r = 0; r < 4; ++r) {
            int rL = 16 * m + l4 * 4 + r;
            outBuf[rL * 256 + wc * 64 + 16 * n + l15] = acc[m][n][r];
          }
        }
      }
    }
    __syncthreads();
#pragma unroll
    for (int i = 0; i < 4; ++i) {
      int ch = tid + 512 * i;
      int rL = ch >> 6;
      int c4 = ch & 63;
      f32x4 v = *(const f32x4*)(outBuf + rL * 256 + c4 * 4);
      *(f32x4*)(out + (size_t)(orow0 + 32 * h + rL) * Cc + colb * BNf + c4 * 4) = v;
    }
  }
}

// ---------------------------------------------------------------------------
extern "C" void kernel_launch(void* const* d_in, const int* in_sizes, int n_in,
                              void* d_out, int out_size, void* d_ws, size_t ws_size,
                              hipStream_t stream) {
  const float* x   = (const float*)d_in[0];  // [131072,128]
  const float* cen = (const float*)d_in[1];  // [1024,128]
  const float* gam = (const float*)d_in[2];  // [1]
  const float* nrm = (const float*)d_in[3];  // [1024,1024]
  float* out = (float*)d_out;

  const size_t cenbB = (size_t)Cc * Dk * 2;            // 256 KB
  const size_t c2B   = (size_t)Cc * 4;                 // 4 KB
  const size_t nTB   = (size_t)Cc * Cc * 2;            // 2 MB
  const size_t pFull = (size_t)Nrows * Cc * 2;         // 268 MB
  const size_t pChB  = (size_t)CH * Cc * 2;            // 33.5 MB

  if (ws_size >= cenbB + c2B + nTB + pFull) {
    // full split path: one kexp, one 256^2 8-phase GEMM
    uint16_t* cenb = (uint16_t*)d_ws;
    float*    c2   = (float*)((char*)d_ws + cenbB);
    uint16_t* nT   = (uint16_t*)((char*)d_ws + cenbB + c2B);
    uint16_t* Pws  = (uint16_t*)((char*)d_ws + cenbB + c2B + nTB);
    prep_cen<<<64, 256, 0, stream>>>(cen, cenb, c2);
    prep_nT<<<256, 256, 0, stream>>>(nrm, nT);
    kexp<<<(Nrows / 128) * 8, 256, 66048, stream>>>(x, gam, cenb, c2, Pws, 0);
    g2_8p<<<(Nrows / 256) * 4, 512, 131072, stream>>>(Pws, nT, out, 0, Nrows / 256);
  } else if (ws_size >= cenbB + c2B + nTB + pChB) {
    // chunked split path
    uint16_t* cenb = (uint16_t*)d_ws;
    float*    c2   = (float*)((char*)d_ws + cenbB);
    uint16_t* nT   = (uint16_t*)((char*)d_ws + cenbB + c2B);
    uint16_t* Pws  = (uint16_t*)((char*)d_ws + cenbB + c2B + nTB);
    prep_cen<<<64, 256, 0, stream>>>(cen, cenb, c2);
    prep_nT<<<256, 256, 0, stream>>>(nrm, nT);
    for (int c = 0; c < NCHUNK; ++c) {
      kexp<<<(CH / 128) * 8, 256, 66048, stream>>>(x, gam, cenb, c2, Pws, c * CH);
      g2_8p<<<(CH / 256) * 4, 512, 131072, stream>>>(Pws, nT, out, c * CH, CH / 256);
    }
  } else if (ws_size >= cenbB + c2B + nTB) {
    uint16_t* cenb = (uint16_t*)d_ws;
    float*    c2   = (float*)((char*)d_ws + cenbB);
    uint16_t* nT   = (uint16_t*)((char*)d_ws + cenbB + c2B);
    prep_cen<<<64, 256, 0, stream>>>(cen, cenb, c2);
    prep_nT<<<256, 256, 0, stream>>>(nrm, nT);
    nyst_main<1><<<(Nrows / BMf) * (Cc / BNf), 512, LDS_MAIN, stream>>>(
        x, cen, gam, nrm, cenb, c2, nT, out);
  } else {
    nyst_main<0><<<(Nrows / BMf) * (Cc / BNf), 512, LDS_FB, stream>>>(
        x, cen, gam, nrm, nullptr, nullptr, nullptr, out);
  }
}

// Round 9
// 451.606 us; speedup vs baseline: 5.3116x; 1.2235x over previous
//
#include <hip/hip_runtime.h>
#include <stdint.h>

typedef float    f32x4  __attribute__((ext_vector_type(4)));
typedef __bf16   bf16x8 __attribute__((ext_vector_type(8)));
typedef uint16_t u16x8  __attribute__((ext_vector_type(8)));
typedef uint16_t u16x4  __attribute__((ext_vector_type(4)));

static __device__ __forceinline__ f32x4 mfma_bf16(bf16x8 a, bf16x8 b, f32x4 c) {
  return __builtin_amdgcn_mfma_f32_16x16x32_bf16(a, b, c, 0, 0, 0);
}
// fp32 -> bf16 round-to-nearest-even
static __device__ __forceinline__ uint16_t f2bf(float f) {
  uint32_t u = __builtin_bit_cast(uint32_t, f);
  u += 0x7fffu + ((u >> 16) & 1u);
  return (uint16_t)(u >> 16);
}
// async global->LDS, 16B per lane (gfx950). dest must be linear-in-lane.
static __device__ __forceinline__ void gload16(const void* src, void* lds) {
  __builtin_amdgcn_global_load_lds(
      (const __attribute__((address_space(1))) void*)src,
      (__attribute__((address_space(3))) void*)lds, 16, 0, 0);
}

constexpr int Nrows = 131072;
constexpr int Dk    = 128;
constexpr int Cc    = 1024;
constexpr int CH     = 16384;          // rows per chunk (mid-ws fallback)
constexpr int NCHUNK = Nrows / CH;     // 8
// fused fallback (R5) geometry
constexpr int BMf   = 64;
constexpr int BNf   = 256;
constexpr int KBf   = 128;
constexpr int XBYTES = BMf * Dk * 2;
constexpr int PBYTES = BMf * KBf * 2;
constexpr int LDS_MAIN = XBYTES + PBYTES + BMf * 4;
constexpr int LDS_FB   = LDS_MAIN + Cc * 4;
constexpr int KEXP2_LDS = 32768 * 3 + 34816 + 512;   // 133632

// ---------------------------------------------------------------------------
// Prep A: centers -> bf16 [C][D], and c2[C]
// ---------------------------------------------------------------------------
__global__ void prep_cen(const float* __restrict__ cen,
                         uint16_t* __restrict__ cenb,
                         float* __restrict__ c2) {
  const int t = threadIdx.x;
  const int row = blockIdx.x * 16 + (t >> 4);
  const int q = t & 15;
  const float* src = cen + (size_t)row * Dk + q * 8;
  f32x4 v0 = *(const f32x4*)src;
  f32x4 v1 = *(const f32x4*)(src + 4);
  u16x8 h;
  float ss = 0.f;
#pragma unroll
  for (int i = 0; i < 4; ++i) {
    h[i]     = f2bf(v0[i]); ss += v0[i] * v0[i];
    h[i + 4] = f2bf(v1[i]); ss += v1[i] * v1[i];
  }
  *(u16x8*)(cenb + (size_t)row * Dk + q * 8) = h;
  ss += __shfl_xor(ss, 1);
  ss += __shfl_xor(ss, 2);
  ss += __shfl_xor(ss, 4);
  ss += __shfl_xor(ss, 8);
  if (q == 0) c2[row] = ss;
}

// ---------------------------------------------------------------------------
// Prep B: nT[j][c] = bf16(norm[c][j])
// ---------------------------------------------------------------------------
__global__ void prep_nT(const float* __restrict__ nrm, uint16_t* __restrict__ nT) {
  __shared__ float tile[64][65];
  const int jb = blockIdx.x & 15;
  const int cb = blockIdx.x >> 4;
  const int t  = threadIdx.x;
  const int r  = t >> 4;
  const int q  = t & 15;
#pragma unroll
  for (int i = 0; i < 4; ++i) {
    int row = r + i * 16;
    f32x4 v = *(const f32x4*)(nrm + (size_t)(cb * 64 + row) * Cc + jb * 64 + q * 4);
#pragma unroll
    for (int s = 0; s < 4; ++s) tile[row][q * 4 + s] = v[s];
  }
  __syncthreads();
#pragma unroll
  for (int i = 0; i < 4; ++i) {
    int j = r + i * 16;
    u16x4 hs;
#pragma unroll
    for (int s = 0; s < 4; ++s) hs[s] = f2bf(tile[q * 4 + s][j]);
    *(u16x4*)(nT + (size_t)(jb * 64 + j) * Cc + cb * 64 + q * 4) = hs;
  }
}

// ---------------------------------------------------------------------------
// kexp2: one block per 128-row stripe; colb-loop INSIDE (x read once).
// cenb tiles double-buffered via gload_lds with counted vmcnt; xB/cB
// XOR-swizzled (both-sides rule: linear gload dest + swizzled global src +
// swizzled ds_read). pbuf (stride 272B) bounces exp output to coalesced P.
// ---------------------------------------------------------------------------
__global__ __launch_bounds__(512, 2) void kexp2(
    const float* __restrict__ x, const float* __restrict__ gam,
    const uint16_t* __restrict__ cenb, const float* __restrict__ c2g,
    uint16_t* __restrict__ P, int row0) {
  extern __shared__ char smem[];
  char*     xB   = smem;                           // [128] rows x 16 chunks, swz
  char*     cB0  = smem + 32768;
  char*     cB1  = smem + 65536;
  uint16_t* pbuf = (uint16_t*)(smem + 98304);      // [128][136] u16 (272B stride)
  float*    x2s  = (float*)(smem + 98304 + 34816); // [128]

  const int tid  = threadIdx.x;
  const int lane = tid & 63;
  const int wid  = tid >> 6;     // 0..7
  const int wr   = wid >> 2;     // 0..1 : 64-row half
  const int wn   = wid & 3;      // 0..3 : 32-col quarter
  const int l15  = lane & 15;
  const int l4   = lane >> 4;
  const int mb   = blockIdx.x;

  auto stage_c = [&](char* db, int ct) {
#pragma unroll
    for (int i = 0; i < 4; ++i) {
      int ch = tid + i * 512;    // 2048 chunks of 16B
      int r  = ch >> 4;
      int c  = ch & 15;
      gload16(cenb + (size_t)(ct * 128 + r) * Dk + ((c ^ (r & 7)) * 8),
              db + ch * 16);
    }
  };
  stage_c(cB0, 0);  // prologue: tile 0 in flight under the x staging below

  // ---- stage x (f32 -> bf16, swizzled) + x2 row sums ----
  const float* xblk = x + (size_t)(row0 + mb * 128) * Dk;
#pragma unroll
  for (int it = 0; it < 4; ++it) {
    int ch = tid + it * 512;
    int r  = ch >> 4;
    int cc = ch & 15;
    const float* src = xblk + r * Dk + cc * 8;
    f32x4 v0 = __builtin_nontemporal_load((const f32x4*)src);
    f32x4 v1 = __builtin_nontemporal_load((const f32x4*)(src + 4));
    u16x8 hh;
    float ss = 0.f;
#pragma unroll
    for (int i = 0; i < 4; ++i) {
      hh[i]     = f2bf(v0[i]); ss += v0[i] * v0[i];
      hh[i + 4] = f2bf(v1[i]); ss += v1[i] * v1[i];
    }
    *(u16x8*)(xB + r * 256 + ((cc ^ (r & 7)) * 16)) = hh;
    ss += __shfl_xor(ss, 1);
    ss += __shfl_xor(ss, 2);
    ss += __shfl_xor(ss, 4);
    ss += __shfl_xor(ss, 8);
    if ((tid & 15) == 0) x2s[r] = ss;
  }

  const float ngam = -gam[0];

  for (int ct = 0; ct < 8; ++ct) {
    char* cC = (ct & 1) ? cB1 : cB0;
    char* cN = (ct & 1) ? cB0 : cB1;
    if (ct < 7) stage_c(cN, ct + 1);
    // vmcnt: drain this tile's 4 loads; newest {4 copy-stores, 4 new loads}
    // may stay in flight (stores are older than new loads -> 8 covers both).
    if (ct == 0 || ct == 7) asm volatile("s_waitcnt vmcnt(4)" ::: "memory");
    else                    asm volatile("s_waitcnt vmcnt(8)" ::: "memory");
    __builtin_amdgcn_s_barrier();

    f32x4 cr[4][2];
#pragma unroll
    for (int m = 0; m < 4; ++m)
#pragma unroll
      for (int n = 0; n < 2; ++n) cr[m][n] = f32x4{0.f, 0.f, 0.f, 0.f};

#pragma unroll
    for (int kk = 0; kk < 4; ++kk) {
      bf16x8 aF[4], bF[2];
#pragma unroll
      for (int m = 0; m < 4; ++m) {
        int row = wr * 64 + m * 16 + l15;
        aF[m] = *(const bf16x8*)(xB + row * 256 +
                                 (((kk * 4 + l4) ^ (row & 7)) * 16));
      }
#pragma unroll
      for (int n = 0; n < 2; ++n) {
        int col = wn * 32 + n * 16 + l15;
        bF[n] = *(const bf16x8*)(cC + col * 256 +
                                 (((kk * 4 + l4) ^ (col & 7)) * 16));
      }
#pragma unroll
      for (int m = 0; m < 4; ++m)
#pragma unroll
        for (int n = 0; n < 2; ++n) cr[m][n] = mfma_bf16(aF[m], bF[n], cr[m][n]);
    }

    // exp -> pbuf (272B stride breaks write conflicts)
    float c2v[2];
#pragma unroll
    for (int n = 0; n < 2; ++n) c2v[n] = c2g[ct * 128 + wn * 32 + n * 16 + l15];
#pragma unroll
    for (int m = 0; m < 4; ++m) {
#pragma unroll
      for (int n = 0; n < 2; ++n) {
#pragma unroll
        for (int rr = 0; rr < 4; ++rr) {
          int row = wr * 64 + m * 16 + l4 * 4 + rr;
          float s = fmaxf(fmaf(-2.f, cr[m][n][rr], x2s[row] + c2v[n]), 0.f);
          pbuf[row * 136 + wn * 32 + n * 16 + l15] = f2bf(__expf(ngam * s));
        }
      }
    }
    __builtin_amdgcn_s_barrier();
    // coalesced copy pbuf -> P
#pragma unroll
    for (int it = 0; it < 4; ++it) {
      int ch = tid + it * 512;
      int r  = ch >> 4;
      int cc = ch & 15;
      *(u16x8*)(P + (size_t)(mb * 128 + r) * Cc + ct * 128 + cc * 8) =
          *(const u16x8*)((const char*)pbuf + r * 272 + cc * 16);
    }
  }
}

// ---------------------------------------------------------------------------
// g2_8p v2: out = P @ nT^T, 256x256 tile, BK=64, 8 waves (2Mx4N), 128 KB LDS
// double-buffer. DEEP prefetch: ALL 8 stage loads of tile kt+1 are issued at
// the top of tile kt (both buffers free then), so tile kt's loads get a full
// tile (~4 phases) of latency cover; vmcnt(8) counted wait (drain-to-0 only
// at the last tile). 2 raw barriers per tile. T2 swizzle both-sides.
// ---------------------------------------------------------------------------
__global__ __launch_bounds__(512, 2) void g2_8p(
    const uint16_t* __restrict__ P, const uint16_t* __restrict__ nT,
    float* __restrict__ out, int row0, int mblocks) {
  extern __shared__ char smem[];
  char* a0 = smem;
  char* b0 = smem + 32768;
  char* a1 = smem + 65536;
  char* b1 = smem + 98304;

  const int tid  = threadIdx.x;
  const int lane = tid & 63;
  const int wid  = tid >> 6;      // 0..7
  const int wm   = wid >> 2;      // 0..1
  const int wn   = wid & 3;       // 0..3
  const int l15  = lane & 15;
  const int l4   = lane >> 4;

  // bijective XCD swizzle (nwg % 8 == 0): nb fastest within an XCD's chunk ->
  // nT panel (512 KB) + A tiles L2-resident per XCD.
  const int nwg  = mblocks * 4;
  const int cpx  = nwg >> 3;
  const int wgid = (blockIdx.x & 7) * cpx + (blockIdx.x >> 3);
  const int nb   = wgid & 3;
  const int mb   = wgid >> 2;

  const uint16_t* Abase = P + (size_t)mb * 256 * Cc;
  const uint16_t* Bbase = nT + (size_t)nb * 256 * Cc;

  f32x4 acc[8][4];
#pragma unroll
  for (int m = 0; m < 8; ++m)
#pragma unroll
    for (int n = 0; n < 4; ++n) acc[m][n] = f32x4{0.f, 0.f, 0.f, 0.f};

  // stage a full K-tile (A 32KB + B 32KB): 8 gloads/thread, source-swizzled
  auto stage_tile = [&](char* da, char* db, int k0) {
#pragma unroll
    for (int i = 0; i < 4; ++i) {
      int ch = tid + i * 512;
      int r = ch >> 3, c = ch & 7;
      gload16(Abase + (size_t)r * Cc + k0 + ((c ^ (r & 7)) * 8), da + ch * 16);
    }
#pragma unroll
    for (int i = 0; i < 4; ++i) {
      int ch = tid + i * 512;
      int r = ch >> 3, c = ch & 7;
      gload16(Bbase + (size_t)r * Cc + k0 + ((c ^ (r & 7)) * 8), db + ch * 16);
    }
  };

  stage_tile(a0, b0, 0);

  for (int kt = 0; kt < 16; ++kt) {
    char* aC = (kt & 1) ? a1 : a0;
    char* bC = (kt & 1) ? b1 : b0;
    char* aN = (kt & 1) ? a0 : a1;
    char* bN = (kt & 1) ? b0 : b1;
    if (kt < 15) {
      stage_tile(aN, bN, (kt + 1) * 64);
      asm volatile("s_waitcnt vmcnt(8)" ::: "memory");   // tile kt landed
    } else {
      asm volatile("s_waitcnt vmcnt(0)" ::: "memory");
    }
    __builtin_amdgcn_s_barrier();

    bf16x8 bF[4][2];
#pragma unroll
    for (int n = 0; n < 4; ++n)
#pragma unroll
      for (int kk = 0; kk < 2; ++kk) {
        int row = wn * 64 + n * 16 + l15;
        bF[n][kk] = *(const bf16x8*)(bC + row * 128 +
                                     (((kk * 4 + l4) ^ (row & 7)) * 16));
      }
#pragma unroll
    for (int p = 0; p < 4; ++p) {
      bf16x8 aF[2][2];
#pragma unroll
      for (int mm = 0; mm < 2; ++mm)
#pragma unroll
        for (int kk = 0; kk < 2; ++kk) {
          int row = wm * 128 + (2 * p + mm) * 16 + l15;
          aF[mm][kk] = *(const bf16x8*)(aC + row * 128 +
                                        (((kk * 4 + l4) ^ (row & 7)) * 16));
        }
      __builtin_amdgcn_s_setprio(1);
#pragma unroll
      for (int mm = 0; mm < 2; ++mm)
#pragma unroll
        for (int n = 0; n < 4; ++n)
#pragma unroll
          for (int kk = 0; kk < 2; ++kk)
            acc[2 * p + mm][n] = mfma_bf16(aF[mm][kk], bF[n][kk], acc[2 * p + mm][n]);
      __builtin_amdgcn_s_setprio(0);
    }
    __builtin_amdgcn_s_barrier();   // all reads of tile kt done -> buffer free
  }

  // epilogue: bounce halves (128 rows x 256 f32 = 128 KB) -> coalesced stores
  float* obuf = (float*)smem;
#pragma unroll
  for (int h = 0; h < 2; ++h) {
    __syncthreads();
    if (wm == h) {
#pragma unroll
      for (int m = 0; m < 8; ++m)
#pragma unroll
        for (int n = 0; n < 4; ++n)
#pragma unroll
          for (int r = 0; r < 4; ++r) {
            int rL = m * 16 + l4 * 4 + r;  // 0..127
            obuf[rL * 256 + wn * 64 + 16 * n + l15] = acc[m][n][r];
          }
    }
    __syncthreads();
#pragma unroll
    for (int i = 0; i < 16; ++i) {
      int ch = tid + i * 512;   // 8192 chunks of 16B
      int rL = ch >> 6;         // 0..127
      int c4 = ch & 63;
      *(f32x4*)(out + (size_t)(row0 + mb * 256 + h * 128 + rL) * Cc +
                nb * 256 + c4 * 4) = *(const f32x4*)(obuf + rL * 256 + c4 * 4);
    }
  }
}

// ---------------------------------------------------------------------------
// Fused fallback (R5) — only used when ws is too small for the split path.
// ---------------------------------------------------------------------------
template <int USE_NT>
__global__ __launch_bounds__(512, 4) void nyst_main(
    const float* __restrict__ x, const float* __restrict__ cen,
    const float* __restrict__ gam, const float* __restrict__ nrm,
    const uint16_t* __restrict__ cenb, const float* __restrict__ c2g,
    const uint16_t* __restrict__ nT, float* __restrict__ out) {
  extern __shared__ char smem[];
  char*  xB  = smem;
  char*  pB  = smem + XBYTES;
  float* x2s = (float*)(smem + XBYTES + PBYTES);
  float* c2s = (float*)(smem + LDS_MAIN);

  const int tid  = threadIdx.x;
  const int lane = tid & 63;
  const int wid  = tid >> 6;
  const int wr   = wid >> 2;
  const int wc   = wid & 3;
  const int xcd  = blockIdx.x & 7;
  const int bi   = blockIdx.x >> 3;
  const int colb = xcd >> 1;
  const int rowb = (bi << 1) | (xcd & 1);
  const int l15  = lane & 15;
  const int l4   = lane >> 4;

  const float* xblk = x + (size_t)rowb * BMf * Dk;

#pragma unroll
  for (int it = 0; it < 2; ++it) {
    int ch = tid + it * 512;
    int r  = ch >> 4;
    int cc = ch & 15;
    const float* src = xblk + r * Dk + cc * 8;
    f32x4 v0 = __builtin_nontemporal_load((const f32x4*)src);
    f32x4 v1 = __builtin_nontemporal_load((const f32x4*)(src + 4));
    u16x8 hh;
    float ss = 0.f;
#pragma unroll
    for (int i = 0; i < 4; ++i) {
      hh[i]     = f2bf(v0[i]); ss += v0[i] * v0[i];
      hh[i + 4] = f2bf(v1[i]); ss += v1[i] * v1[i];
    }
    int off = (r * 256 + cc * 16) ^ ((r & 7) << 4);
    *(u16x8*)(xB + off) = hh;
    ss += __shfl_xor(ss, 1);
    ss += __shfl_xor(ss, 2);
    ss += __shfl_xor(ss, 4);
    ss += __shfl_xor(ss, 8);
    if ((tid & 15) == 0) x2s[r] = ss;
  }
  if (!USE_NT) {
#pragma unroll
    for (int rr = 0; rr < 2; ++rr) {
      int r = tid + rr * 512;
      const float* src = cen + (size_t)r * Dk;
      float ss = 0.f;
      for (int k = 0; k < Dk / 4; ++k) {
        f32x4 v = *(const f32x4*)(src + 4 * k);
        ss += v[0] * v[0] + v[1] * v[1] + v[2] * v[2] + v[3] * v[3];
      }
      c2s[r] = ss;
    }
  }
  __syncthreads();

  const float ngam = -gam[0];
  f32x4 zero4 = {0.f, 0.f, 0.f, 0.f};
  f32x4 acc[2][4];
#pragma unroll
  for (int m = 0; m < 2; ++m)
#pragma unroll
    for (int n = 0; n < 4; ++n) acc[m][n] = zero4;

  for (int c0 = 0; c0 < Cc; c0 += KBf) {
    f32x4 cr[2][2];
#pragma unroll
    for (int g = 0; g < 2; ++g)
#pragma unroll
      for (int m = 0; m < 2; ++m) cr[g][m] = zero4;

#pragma unroll
    for (int kk = 0; kk < 4; ++kk) {
      bf16x8 b0, b1;
      if (USE_NT) {
        int c0col = c0 + 16 * wc + l15;
        b0 = *(const bf16x8*)(cenb + (size_t)c0col * Dk + kk * 32 + l4 * 8);
        b1 = *(const bf16x8*)(cenb + (size_t)(c0col + 64) * Dk + kk * 32 + l4 * 8);
      } else {
#pragma unroll
        for (int g = 0; g < 2; ++g) {
          int ccol = c0 + g * 64 + 16 * wc + l15;
          const float* cb_ = cen + (size_t)ccol * Dk + kk * 32 + l4 * 8;
          f32x4 v0 = *(const f32x4*)cb_;
          f32x4 v1 = *(const f32x4*)(cb_ + 4);
          u16x8 tt;
#pragma unroll
          for (int i = 0; i < 4; ++i) { tt[i] = f2bf(v0[i]); tt[i + 4] = f2bf(v1[i]); }
          if (g == 0) b0 = __builtin_bit_cast(bf16x8, tt);
          else        b1 = __builtin_bit_cast(bf16x8, tt);
        }
      }
#pragma unroll
      for (int m = 0; m < 2; ++m) {
        int row = 32 * wr + 16 * m + l15;
        int off = (row * 256 + kk * 64 + l4 * 16) ^ ((row & 7) << 4);
        bf16x8 a = *(const bf16x8*)(xB + off);
        cr[0][m] = mfma_bf16(a, b0, cr[0][m]);
        cr[1][m] = mfma_bf16(a, b1, cr[1][m]);
      }
    }

    __syncthreads();
#pragma unroll
    for (int g = 0; g < 2; ++g) {
      int ccol = c0 + g * 64 + 16 * wc + l15;
      float c2v = USE_NT ? c2g[ccol] : c2s[ccol];
#pragma unroll
      for (int m = 0; m < 2; ++m) {
#pragma unroll
        for (int r = 0; r < 4; ++r) {
          int row = 32 * wr + 16 * m + l4 * 4 + r;
          float s = fmaxf(fmaf(-2.f, cr[g][m][r], x2s[row] + c2v), 0.f);
          float p = __expf(ngam * s);
          int off = (row * 256 + (g * 64 + 16 * wc + l15) * 2) ^ ((row & 7) << 4);
          *(uint16_t*)(pB + off) = f2bf(p);
        }
      }
    }
    __syncthreads();

#pragma unroll
    for (int kk = 0; kk < 4; ++kk) {
      bf16x8 pa[2];
#pragma unroll
      for (int m = 0; m < 2; ++m) {
        int row = 32 * wr + 16 * m + l15;
        int off = (row * 256 + kk * 64 + l4 * 16) ^ ((row & 7) << 4);
        pa[m] = *(const bf16x8*)(pB + off);
      }
      int krow = c0 + kk * 32 + l4 * 8;
#pragma unroll
      for (int n = 0; n < 4; ++n) {
        int j = colb * BNf + wc * 64 + 16 * n + l15;
        bf16x8 bm;
        if (USE_NT) {
          bm = *(const bf16x8*)(nT + (size_t)j * Cc + krow);
        } else {
          u16x8 tt;
#pragma unroll
          for (int i = 0; i < 8; ++i) tt[i] = f2bf(nrm[(size_t)(krow + i) * Cc + j]);
          bm = __builtin_bit_cast(bf16x8, tt);
        }
        acc[0][n] = mfma_bf16(pa[0], bm, acc[0][n]);
        acc[1][n] = mfma_bf16(pa[1], bm, acc[1][n]);
      }
    }
  }

  float* outBuf = (float*)smem;
  const int orow0 = rowb * BMf;
#pragma unroll
  for (int h = 0; h < 2; ++h) {
    __syncthreads();
    if (wr == h) {
#pragma unroll
      for (int m = 0; m < 2; ++m) {
#pragma unroll
        for (int n = 0; n < 4; ++n) {
#pragma unroll
          for (int r = 0; r < 4; ++r) {
            int rL = 16 * m + l4 * 4 + r;
            outBuf[rL * 256 + wc * 64 + 16 * n + l15] = acc[m][n][r];
          }
        }
      }
    }
    __syncthreads();
#pragma unroll
    for (int i = 0; i < 4; ++i) {
      int ch = tid + 512 * i;
      int rL = ch >> 6;
      int c4 = ch & 63;
      f32x4 v = *(const f32x4*)(outBuf + rL * 256 + c4 * 4);
      *(f32x4*)(out + (size_t)(orow0 + 32 * h + rL) * Cc + colb * BNf + c4 * 4) = v;
    }
  }
}

// ---------------------------------------------------------------------------
extern "C" void kernel_launch(void* const* d_in, const int* in_sizes, int n_in,
                              void* d_out, int out_size, void* d_ws, size_t ws_size,
                              hipStream_t stream) {
  const float* x   = (const float*)d_in[0];  // [131072,128]
  const float* cen = (const float*)d_in[1];  // [1024,128]
  const float* gam = (const float*)d_in[2];  // [1]
  const float* nrm = (const float*)d_in[3];  // [1024,1024]
  float* out = (float*)d_out;

  const size_t cenbB = (size_t)Cc * Dk * 2;            // 256 KB
  const size_t c2B   = (size_t)Cc * 4;                 // 4 KB
  const size_t nTB   = (size_t)Cc * Cc * 2;            // 2 MB
  const size_t pFull = (size_t)Nrows * Cc * 2;         // 268 MB
  const size_t pChB  = (size_t)CH * Cc * 2;            // 33.5 MB

  if (ws_size >= cenbB + c2B + nTB + pFull) {
    uint16_t* cenb = (uint16_t*)d_ws;
    float*    c2   = (float*)((char*)d_ws + cenbB);
    uint16_t* nT   = (uint16_t*)((char*)d_ws + cenbB + c2B);
    uint16_t* Pws  = (uint16_t*)((char*)d_ws + cenbB + c2B + nTB);
    prep_cen<<<64, 256, 0, stream>>>(cen, cenb, c2);
    prep_nT<<<256, 256, 0, stream>>>(nrm, nT);
    kexp2<<<Nrows / 128, 512, KEXP2_LDS, stream>>>(x, gam, cenb, c2, Pws, 0);
    g2_8p<<<(Nrows / 256) * 4, 512, 131072, stream>>>(Pws, nT, out, 0, Nrows / 256);
  } else if (ws_size >= cenbB + c2B + nTB + pChB) {
    uint16_t* cenb = (uint16_t*)d_ws;
    float*    c2   = (float*)((char*)d_ws + cenbB);
    uint16_t* nT   = (uint16_t*)((char*)d_ws + cenbB + c2B);
    uint16_t* Pws  = (uint16_t*)((char*)d_ws + cenbB + c2B + nTB);
    prep_cen<<<64, 256, 0, stream>>>(cen, cenb, c2);
    prep_nT<<<256, 256, 0, stream>>>(nrm, nT);
    for (int c = 0; c < NCHUNK; ++c) {
      kexp2<<<CH / 128, 512, KEXP2_LDS, stream>>>(x, gam, cenb, c2, Pws, c * CH);
      g2_8p<<<(CH / 256) * 4, 512, 131072, stream>>>(Pws, nT, out, c * CH, CH / 256);
    }
  } else if (ws_size >= cenbB + c2B + nTB) {
    uint16_t* cenb = (uint16_t*)d_ws;
    float*    c2   = (float*)((char*)d_ws + cenbB);
    uint16_t* nT   = (uint16_t*)((char*)d_ws + cenbB + c2B);
    prep_cen<<<64, 256, 0, stream>>>(cen, cenb, c2);
    prep_nT<<<256, 256, 0, stream>>>(nrm, nT);
    nyst_main<1><<<(Nrows / BMf) * (Cc / BNf), 512, LDS_MAIN, stream>>>(
        x, cen, gam, nrm, cenb, c2, nT, out);
  } else {
    nyst_main<0><<<(Nrows / BMf) * (Cc / BNf), 512, LDS_FB, stream>>>(
        x, cen, gam, nrm, nullptr, nullptr, nullptr, out);
  }
}

// Round 10
// 409.660 us; speedup vs baseline: 5.8555x; 1.1024x over previous
//
#include <hip/hip_runtime.h>
#include <stdint.h>

typedef float    f32x4  __attribute__((ext_vector_type(4)));
typedef __bf16   bf16x8 __attribute__((ext_vector_type(8)));
typedef uint16_t u16x8  __attribute__((ext_vector_type(8)));
typedef uint16_t u16x4  __attribute__((ext_vector_type(4)));

static __device__ __forceinline__ f32x4 mfma_bf16(bf16x8 a, bf16x8 b, f32x4 c) {
  return __builtin_amdgcn_mfma_f32_16x16x32_bf16(a, b, c, 0, 0, 0);
}
// fp32 -> bf16 round-to-nearest-even
static __device__ __forceinline__ uint16_t f2bf(float f) {
  uint32_t u = __builtin_bit_cast(uint32_t, f);
  u += 0x7fffu + ((u >> 16) & 1u);
  return (uint16_t)(u >> 16);
}
// async global->LDS, 16B per lane (gfx950). dest must be linear-in-lane.
static __device__ __forceinline__ void gload16(const void* src, void* lds) {
  __builtin_amdgcn_global_load_lds(
      (const __attribute__((address_space(1))) void*)src,
      (__attribute__((address_space(3))) void*)lds, 16, 0, 0);
}

constexpr int Nrows = 131072;
constexpr int Dk    = 128;
constexpr int Cc    = 1024;
constexpr int CH     = 16384;          // rows per chunk (mid-ws fallback)
constexpr int NCHUNK = Nrows / CH;     // 8
// fused fallback (R5) geometry
constexpr int BMf   = 64;
constexpr int BNf   = 256;
constexpr int KBf   = 128;
constexpr int XBYTES = BMf * Dk * 2;
constexpr int PBYTES = BMf * KBf * 2;
constexpr int LDS_MAIN = XBYTES + PBYTES + BMf * 4;
constexpr int LDS_FB   = LDS_MAIN + Cc * 4;
constexpr int KEXP2_LDS = 32768 * 3 + 34816 + 512;   // 133632

// ---------------------------------------------------------------------------
// Prep A: centers -> bf16 [C][D], and c2[C]
// ---------------------------------------------------------------------------
__global__ void prep_cen(const float* __restrict__ cen,
                         uint16_t* __restrict__ cenb,
                         float* __restrict__ c2) {
  const int t = threadIdx.x;
  const int row = blockIdx.x * 16 + (t >> 4);
  const int q = t & 15;
  const float* src = cen + (size_t)row * Dk + q * 8;
  f32x4 v0 = *(const f32x4*)src;
  f32x4 v1 = *(const f32x4*)(src + 4);
  u16x8 h;
  float ss = 0.f;
#pragma unroll
  for (int i = 0; i < 4; ++i) {
    h[i]     = f2bf(v0[i]); ss += v0[i] * v0[i];
    h[i + 4] = f2bf(v1[i]); ss += v1[i] * v1[i];
  }
  *(u16x8*)(cenb + (size_t)row * Dk + q * 8) = h;
  ss += __shfl_xor(ss, 1);
  ss += __shfl_xor(ss, 2);
  ss += __shfl_xor(ss, 4);
  ss += __shfl_xor(ss, 8);
  if (q == 0) c2[row] = ss;
}

// ---------------------------------------------------------------------------
// Prep B: nT[j][c] = bf16(norm[c][j])
// ---------------------------------------------------------------------------
__global__ void prep_nT(const float* __restrict__ nrm, uint16_t* __restrict__ nT) {
  __shared__ float tile[64][65];
  const int jb = blockIdx.x & 15;
  const int cb = blockIdx.x >> 4;
  const int t  = threadIdx.x;
  const int r  = t >> 4;
  const int q  = t & 15;
#pragma unroll
  for (int i = 0; i < 4; ++i) {
    int row = r + i * 16;
    f32x4 v = *(const f32x4*)(nrm + (size_t)(cb * 64 + row) * Cc + jb * 64 + q * 4);
#pragma unroll
    for (int s = 0; s < 4; ++s) tile[row][q * 4 + s] = v[s];
  }
  __syncthreads();
#pragma unroll
  for (int i = 0; i < 4; ++i) {
    int j = r + i * 16;
    u16x4 hs;
#pragma unroll
    for (int s = 0; s < 4; ++s) hs[s] = f2bf(tile[q * 4 + s][j]);
    *(u16x4*)(nT + (size_t)(jb * 64 + j) * Cc + cb * 64 + q * 4) = hs;
  }
}

// ---------------------------------------------------------------------------
// kexp2: one block per 128-row stripe; colb-loop INSIDE (x read once).
// cenb tiles double-buffered via gload_lds with counted vmcnt; xB/cB
// XOR-swizzled (both-sides rule). pbuf bounces exp output to coalesced P.
// (proven R9: ~74 us, near BW floor)
// ---------------------------------------------------------------------------
__global__ __launch_bounds__(512, 2) void kexp2(
    const float* __restrict__ x, const float* __restrict__ gam,
    const uint16_t* __restrict__ cenb, const float* __restrict__ c2g,
    uint16_t* __restrict__ P, int row0) {
  extern __shared__ char smem[];
  char*     xB   = smem;                           // [128] rows x 16 chunks, swz
  char*     cB0  = smem + 32768;
  char*     cB1  = smem + 65536;
  uint16_t* pbuf = (uint16_t*)(smem + 98304);      // [128][136] u16 (272B stride)
  float*    x2s  = (float*)(smem + 98304 + 34816); // [128]

  const int tid  = threadIdx.x;
  const int lane = tid & 63;
  const int wid  = tid >> 6;     // 0..7
  const int wr   = wid >> 2;     // 0..1 : 64-row half
  const int wn   = wid & 3;      // 0..3 : 32-col quarter
  const int l15  = lane & 15;
  const int l4   = lane >> 4;
  const int mb   = blockIdx.x;

  auto stage_c = [&](char* db, int ct) {
#pragma unroll
    for (int i = 0; i < 4; ++i) {
      int ch = tid + i * 512;    // 2048 chunks of 16B
      int r  = ch >> 4;
      int c  = ch & 15;
      gload16(cenb + (size_t)(ct * 128 + r) * Dk + ((c ^ (r & 7)) * 8),
              db + ch * 16);
    }
  };
  stage_c(cB0, 0);  // prologue: tile 0 in flight under the x staging below

  // ---- stage x (f32 -> bf16, swizzled) + x2 row sums ----
  const float* xblk = x + (size_t)(row0 + mb * 128) * Dk;
#pragma unroll
  for (int it = 0; it < 4; ++it) {
    int ch = tid + it * 512;
    int r  = ch >> 4;
    int cc = ch & 15;
    const float* src = xblk + r * Dk + cc * 8;
    f32x4 v0 = __builtin_nontemporal_load((const f32x4*)src);
    f32x4 v1 = __builtin_nontemporal_load((const f32x4*)(src + 4));
    u16x8 hh;
    float ss = 0.f;
#pragma unroll
    for (int i = 0; i < 4; ++i) {
      hh[i]     = f2bf(v0[i]); ss += v0[i] * v0[i];
      hh[i + 4] = f2bf(v1[i]); ss += v1[i] * v1[i];
    }
    *(u16x8*)(xB + r * 256 + ((cc ^ (r & 7)) * 16)) = hh;
    ss += __shfl_xor(ss, 1);
    ss += __shfl_xor(ss, 2);
    ss += __shfl_xor(ss, 4);
    ss += __shfl_xor(ss, 8);
    if ((tid & 15) == 0) x2s[r] = ss;
  }

  const float ngam = -gam[0];

  for (int ct = 0; ct < 8; ++ct) {
    char* cC = (ct & 1) ? cB1 : cB0;
    char* cN = (ct & 1) ? cB0 : cB1;
    if (ct < 7) stage_c(cN, ct + 1);
    if (ct == 0 || ct == 7) asm volatile("s_waitcnt vmcnt(4)" ::: "memory");
    else                    asm volatile("s_waitcnt vmcnt(8)" ::: "memory");
    __builtin_amdgcn_s_barrier();

    f32x4 cr[4][2];
#pragma unroll
    for (int m = 0; m < 4; ++m)
#pragma unroll
      for (int n = 0; n < 2; ++n) cr[m][n] = f32x4{0.f, 0.f, 0.f, 0.f};

#pragma unroll
    for (int kk = 0; kk < 4; ++kk) {
      bf16x8 aF[4], bF[2];
#pragma unroll
      for (int m = 0; m < 4; ++m) {
        int row = wr * 64 + m * 16 + l15;
        aF[m] = *(const bf16x8*)(xB + row * 256 +
                                 (((kk * 4 + l4) ^ (row & 7)) * 16));
      }
#pragma unroll
      for (int n = 0; n < 2; ++n) {
        int col = wn * 32 + n * 16 + l15;
        bF[n] = *(const bf16x8*)(cC + col * 256 +
                                 (((kk * 4 + l4) ^ (col & 7)) * 16));
      }
#pragma unroll
      for (int m = 0; m < 4; ++m)
#pragma unroll
        for (int n = 0; n < 2; ++n) cr[m][n] = mfma_bf16(aF[m], bF[n], cr[m][n]);
    }

    float c2v[2];
#pragma unroll
    for (int n = 0; n < 2; ++n) c2v[n] = c2g[ct * 128 + wn * 32 + n * 16 + l15];
#pragma unroll
    for (int m = 0; m < 4; ++m) {
#pragma unroll
      for (int n = 0; n < 2; ++n) {
#pragma unroll
        for (int rr = 0; rr < 4; ++rr) {
          int row = wr * 64 + m * 16 + l4 * 4 + rr;
          float s = fmaxf(fmaf(-2.f, cr[m][n][rr], x2s[row] + c2v[n]), 0.f);
          pbuf[row * 136 + wn * 32 + n * 16 + l15] = f2bf(__expf(ngam * s));
        }
      }
    }
    __builtin_amdgcn_s_barrier();
#pragma unroll
    for (int it = 0; it < 4; ++it) {
      int ch = tid + it * 512;
      int r  = ch >> 4;
      int cc = ch & 15;
      *(u16x8*)(P + (size_t)(mb * 128 + r) * Cc + ct * 128 + cc * 8) =
          *(const u16x8*)((const char*)pbuf + r * 272 + cc * 16);
    }
  }
}

// ---------------------------------------------------------------------------
// g2_8p v3: out = P @ nT^T, 256x256 tile, BK=64, 8 waves (2Mx4N), 128 KB LDS
// double-buffer. m201-style vmcnt(6) schedule derived from region lifetimes:
//   B region of tile T is dead after (T,p0) [bF reg-cached]; A after (T,p3).
//   Staging slots: (T,p0): A-half0(T+1); (T,p1): A-half1(T+1) + B-half0(T+2)
//   [into the CURRENT B buffer, freed by p0's exit barrier]; (T,p2):
//   B-half1(T+2). Wait vmcnt(6) at each (T,p0) -- allows {B(T+2) partial,
//   A0(T+1)} in flight; drain 0 only at T=15. Spread issue per phase (m196).
// ---------------------------------------------------------------------------
__global__ __launch_bounds__(512, 2) void g2_8p(
    const uint16_t* __restrict__ P, const uint16_t* __restrict__ nT,
    float* __restrict__ out, int row0, int mblocks) {
  extern __shared__ char smem[];
  char* a0 = smem;
  char* b0 = smem + 32768;
  char* a1 = smem + 65536;
  char* b1 = smem + 98304;

  const int tid  = threadIdx.x;
  const int lane = tid & 63;
  const int wid  = tid >> 6;      // 0..7
  const int wm   = wid >> 2;      // 0..1
  const int wn   = wid & 3;       // 0..3
  const int l15  = lane & 15;
  const int l4   = lane >> 4;

  // bijective XCD swizzle (nwg % 8 == 0): nb fastest within an XCD's chunk.
  const int nwg  = mblocks * 4;
  const int cpx  = nwg >> 3;
  const int wgid = (blockIdx.x & 7) * cpx + (blockIdx.x >> 3);
  const int nb   = wgid & 3;
  const int mb   = wgid >> 2;

  const uint16_t* Abase = P + (size_t)mb * 256 * Cc;
  const uint16_t* Bbase = nT + (size_t)nb * 256 * Cc;

  f32x4 acc[8][4];
#pragma unroll
  for (int m = 0; m < 8; ++m)
#pragma unroll
    for (int n = 0; n < 4; ++n) acc[m][n] = f32x4{0.f, 0.f, 0.f, 0.f};

  // stage one half-tile (h=0: rows 0-127, h=1: rows 128-255); 2 gloads/thread,
  // source-swizzled (both-sides rule)
  auto stage_half = [&](const uint16_t* gb, char* db, int k0, int h) {
    int ch0 = h * 1024 + tid;
    int ch1 = ch0 + 512;
    int r0 = ch0 >> 3, c0 = ch0 & 7;
    int r1 = ch1 >> 3, c1 = ch1 & 7;
    gload16(gb + (size_t)r0 * Cc + k0 + ((c0 ^ (r0 & 7)) * 8), db + ch0 * 16);
    gload16(gb + (size_t)r1 * Cc + k0 + ((c1 ^ (r1 & 7)) * 8), db + ch1 * 16);
  };

  // prologue: B(0) fully, A(0) fully, B(1) fully  (12 loads/thread-pair order
  // matters: first 8 = B(0)+A(0) are what vmcnt(6) at kt=0 requires done)
  stage_half(Bbase, b0, 0, 0);
  stage_half(Bbase, b0, 0, 1);
  stage_half(Abase, a0, 0, 0);
  stage_half(Abase, a0, 0, 1);
  stage_half(Bbase, b1, 64, 0);
  stage_half(Bbase, b1, 64, 1);

  for (int kt = 0; kt < 16; ++kt) {
    const int q = kt & 1;
    char* aC = q ? a1 : a0;
    char* bC = q ? b1 : b0;
    char* aN = q ? a0 : a1;     // A(kt+1) -> opposite parity (freed (kt-1,p3))

    bf16x8 bF[4][2];
#pragma unroll
    for (int p = 0; p < 4; ++p) {
      // --- per-phase staging slots (issue before this phase's barrier) ---
      if (p == 0) {
        if (kt + 1 < 16) stage_half(Abase, aN, (kt + 1) * 64, 0);
        if (kt == 15) asm volatile("s_waitcnt vmcnt(0)" ::: "memory");
        else          asm volatile("s_waitcnt vmcnt(6)" ::: "memory");
      } else if (p == 1) {
        if (kt + 1 < 16) stage_half(Abase, aN, (kt + 1) * 64, 1);
        if (kt + 2 < 16) stage_half(Bbase, bC, (kt + 2) * 64, 0);  // freed @p0
      } else if (p == 2) {
        if (kt + 2 < 16) stage_half(Bbase, bC, (kt + 2) * 64, 1);
      }
      __builtin_amdgcn_s_barrier();

      if (p == 0) {
#pragma unroll
        for (int n = 0; n < 4; ++n)
#pragma unroll
          for (int kk = 0; kk < 2; ++kk) {
            int row = wn * 64 + n * 16 + l15;
            bF[n][kk] = *(const bf16x8*)(bC + row * 128 +
                                         (((kk * 4 + l4) ^ (row & 7)) * 16));
          }
      }
      bf16x8 aF[2][2];
#pragma unroll
      for (int mm = 0; mm < 2; ++mm)
#pragma unroll
        for (int kk = 0; kk < 2; ++kk) {
          int row = wm * 128 + (2 * p + mm) * 16 + l15;
          aF[mm][kk] = *(const bf16x8*)(aC + row * 128 +
                                        (((kk * 4 + l4) ^ (row & 7)) * 16));
        }
      __builtin_amdgcn_s_setprio(1);
#pragma unroll
      for (int mm = 0; mm < 2; ++mm)
#pragma unroll
        for (int n = 0; n < 4; ++n)
#pragma unroll
          for (int kk = 0; kk < 2; ++kk)
            acc[2 * p + mm][n] = mfma_bf16(aF[mm][kk], bF[n][kk], acc[2 * p + mm][n]);
      __builtin_amdgcn_s_setprio(0);
      __builtin_amdgcn_s_barrier();
    }
  }

  // epilogue: bounce halves (128 rows x 256 f32 = 128 KB) -> coalesced stores
  float* obuf = (float*)smem;
#pragma unroll
  for (int h = 0; h < 2; ++h) {
    __syncthreads();
    if (wm == h) {
#pragma unroll
      for (int m = 0; m < 8; ++m)
#pragma unroll
        for (int n = 0; n < 4; ++n)
#pragma unroll
          for (int r = 0; r < 4; ++r) {
            int rL = m * 16 + l4 * 4 + r;  // 0..127
            obuf[rL * 256 + wn * 64 + 16 * n + l15] = acc[m][n][r];
          }
    }
    __syncthreads();
#pragma unroll
    for (int i = 0; i < 16; ++i) {
      int ch = tid + i * 512;   // 8192 chunks of 16B
      int rL = ch >> 6;         // 0..127
      int c4 = ch & 63;
      *(f32x4*)(out + (size_t)(row0 + mb * 256 + h * 128 + rL) * Cc +
                nb * 256 + c4 * 4) = *(const f32x4*)(obuf + rL * 256 + c4 * 4);
    }
  }
}

// ---------------------------------------------------------------------------
// Fused fallback (R5) — only used when ws is too small for the split path.
// ---------------------------------------------------------------------------
template <int USE_NT>
__global__ __launch_bounds__(512, 4) void nyst_main(
    const float* __restrict__ x, const float* __restrict__ cen,
    const float* __restrict__ gam, const float* __restrict__ nrm,
    const uint16_t* __restrict__ cenb, const float* __restrict__ c2g,
    const uint16_t* __restrict__ nT, float* __restrict__ out) {
  extern __shared__ char smem[];
  char*  xB  = smem;
  char*  pB  = smem + XBYTES;
  float* x2s = (float*)(smem + XBYTES + PBYTES);
  float* c2s = (float*)(smem + LDS_MAIN);

  const int tid  = threadIdx.x;
  const int lane = tid & 63;
  const int wid  = tid >> 6;
  const int wr   = wid >> 2;
  const int wc   = wid & 3;
  const int xcd  = blockIdx.x & 7;
  const int bi   = blockIdx.x >> 3;
  const int colb = xcd >> 1;
  const int rowb = (bi << 1) | (xcd & 1);
  const int l15  = lane & 15;
  const int l4   = lane >> 4;

  const float* xblk = x + (size_t)rowb * BMf * Dk;

#pragma unroll
  for (int it = 0; it < 2; ++it) {
    int ch = tid + it * 512;
    int r  = ch >> 4;
    int cc = ch & 15;
    const float* src = xblk + r * Dk + cc * 8;
    f32x4 v0 = __builtin_nontemporal_load((const f32x4*)src);
    f32x4 v1 = __builtin_nontemporal_load((const f32x4*)(src + 4));
    u16x8 hh;
    float ss = 0.f;
#pragma unroll
    for (int i = 0; i < 4; ++i) {
      hh[i]     = f2bf(v0[i]); ss += v0[i] * v0[i];
      hh[i + 4] = f2bf(v1[i]); ss += v1[i] * v1[i];
    }
    int off = (r * 256 + cc * 16) ^ ((r & 7) << 4);
    *(u16x8*)(xB + off) = hh;
    ss += __shfl_xor(ss, 1);
    ss += __shfl_xor(ss, 2);
    ss += __shfl_xor(ss, 4);
    ss += __shfl_xor(ss, 8);
    if ((tid & 15) == 0) x2s[r] = ss;
  }
  if (!USE_NT) {
#pragma unroll
    for (int rr = 0; rr < 2; ++rr) {
      int r = tid + rr * 512;
      const float* src = cen + (size_t)r * Dk;
      float ss = 0.f;
      for (int k = 0; k < Dk / 4; ++k) {
        f32x4 v = *(const f32x4*)(src + 4 * k);
        ss += v[0] * v[0] + v[1] * v[1] + v[2] * v[2] + v[3] * v[3];
      }
      c2s[r] = ss;
    }
  }
  __syncthreads();

  const float ngam = -gam[0];
  f32x4 zero4 = {0.f, 0.f, 0.f, 0.f};
  f32x4 acc[2][4];
#pragma unroll
  for (int m = 0; m < 2; ++m)
#pragma unroll
    for (int n = 0; n < 4; ++n) acc[m][n] = zero4;

  for (int c0 = 0; c0 < Cc; c0 += KBf) {
    f32x4 cr[2][2];
#pragma unroll
    for (int g = 0; g < 2; ++g)
#pragma unroll
      for (int m = 0; m < 2; ++m) cr[g][m] = zero4;

#pragma unroll
    for (int kk = 0; kk < 4; ++kk) {
      bf16x8 b0, b1;
      if (USE_NT) {
        int c0col = c0 + 16 * wc + l15;
        b0 = *(const bf16x8*)(cenb + (size_t)c0col * Dk + kk * 32 + l4 * 8);
        b1 = *(const bf16x8*)(cenb + (size_t)(c0col + 64) * Dk + kk * 32 + l4 * 8);
      } else {
#pragma unroll
        for (int g = 0; g < 2; ++g) {
          int ccol = c0 + g * 64 + 16 * wc + l15;
          const float* cb_ = cen + (size_t)ccol * Dk + kk * 32 + l4 * 8;
          f32x4 v0 = *(const f32x4*)cb_;
          f32x4 v1 = *(const f32x4*)(cb_ + 4);
          u16x8 tt;
#pragma unroll
          for (int i = 0; i < 4; ++i) { tt[i] = f2bf(v0[i]); tt[i + 4] = f2bf(v1[i]); }
          if (g == 0) b0 = __builtin_bit_cast(bf16x8, tt);
          else        b1 = __builtin_bit_cast(bf16x8, tt);
        }
      }
#pragma unroll
      for (int m = 0; m < 2; ++m) {
        int row = 32 * wr + 16 * m + l15;
        int off = (row * 256 + kk * 64 + l4 * 16) ^ ((row & 7) << 4);
        bf16x8 a = *(const bf16x8*)(xB + off);
        cr[0][m] = mfma_bf16(a, b0, cr[0][m]);
        cr[1][m] = mfma_bf16(a, b1, cr[1][m]);
      }
    }

    __syncthreads();
#pragma unroll
    for (int g = 0; g < 2; ++g) {
      int ccol = c0 + g * 64 + 16 * wc + l15;
      float c2v = USE_NT ? c2g[ccol] : c2s[ccol];
#pragma unroll
      for (int m = 0; m < 2; ++m) {
#pragma unroll
        for (int r = 0; r < 4; ++r) {
          int row = 32 * wr + 16 * m + l4 * 4 + r;
          float s = fmaxf(fmaf(-2.f, cr[g][m][r], x2s[row] + c2v), 0.f);
          float p = __expf(ngam * s);
          int off = (row * 256 + (g * 64 + 16 * wc + l15) * 2) ^ ((row & 7) << 4);
          *(uint16_t*)(pB + off) = f2bf(p);
        }
      }
    }
    __syncthreads();

#pragma unroll
    for (int kk = 0; kk < 4; ++kk) {
      bf16x8 pa[2];
#pragma unroll
      for (int m = 0; m < 2; ++m) {
        int row = 32 * wr + 16 * m + l15;
        int off = (row * 256 + kk * 64 + l4 * 16) ^ ((row & 7) << 4);
        pa[m] = *(const bf16x8*)(pB + off);
      }
      int krow = c0 + kk * 32 + l4 * 8;
#pragma unroll
      for (int n = 0; n < 4; ++n) {
        int j = colb * BNf + wc * 64 + 16 * n + l15;
        bf16x8 bm;
        if (USE_NT) {
          bm = *(const bf16x8*)(nT + (size_t)j * Cc + krow);
        } else {
          u16x8 tt;
#pragma unroll
          for (int i = 0; i < 8; ++i) tt[i] = f2bf(nrm[(size_t)(krow + i) * Cc + j]);
          bm = __builtin_bit_cast(bf16x8, tt);
        }
        acc[0][n] = mfma_bf16(pa[0], bm, acc[0][n]);
        acc[1][n] = mfma_bf16(pa[1], bm, acc[1][n]);
      }
    }
  }

  float* outBuf = (float*)smem;
  const int orow0 = rowb * BMf;
#pragma unroll
  for (int h = 0; h < 2; ++h) {
    __syncthreads();
    if (wr == h) {
#pragma unroll
      for (int m = 0; m < 2; ++m) {
#pragma unroll
        for (int n = 0; n < 4; ++n) {
#pragma unroll
          for (int r = 0; r < 4; ++r) {
            int rL = 16 * m + l4 * 4 + r;
            outBuf[rL * 256 + wc * 64 + 16 * n + l15] = acc[m][n][r];
          }
        }
      }
    }
    __syncthreads();
#pragma unroll
    for (int i = 0; i < 4; ++i) {
      int ch = tid + 512 * i;
      int rL = ch >> 6;
      int c4 = ch & 63;
      f32x4 v = *(const f32x4*)(outBuf + rL * 256 + c4 * 4);
      *(f32x4*)(out + (size_t)(orow0 + 32 * h + rL) * Cc + colb * BNf + c4 * 4) = v;
    }
  }
}

// ---------------------------------------------------------------------------
extern "C" void kernel_launch(void* const* d_in, const int* in_sizes, int n_in,
                              void* d_out, int out_size, void* d_ws, size_t ws_size,
                              hipStream_t stream) {
  const float* x   = (const float*)d_in[0];  // [131072,128]
  const float* cen = (const float*)d_in[1];  // [1024,128]
  const float* gam = (const float*)d_in[2];  // [1]
  const float* nrm = (const float*)d_in[3];  // [1024,1024]
  float* out = (float*)d_out;

  const size_t cenbB = (size_t)Cc * Dk * 2;            // 256 KB
  const size_t c2B   = (size_t)Cc * 4;                 // 4 KB
  const size_t nTB   = (size_t)Cc * Cc * 2;            // 2 MB
  const size_t pFull = (size_t)Nrows * Cc * 2;         // 268 MB
  const size_t pChB  = (size_t)CH * Cc * 2;            // 33.5 MB

  if (ws_size >= cenbB + c2B + nTB + pFull) {
    uint16_t* cenb = (uint16_t*)d_ws;
    float*    c2   = (float*)((char*)d_ws + cenbB);
    uint16_t* nT   = (uint16_t*)((char*)d_ws + cenbB + c2B);
    uint16_t* Pws  = (uint16_t*)((char*)d_ws + cenbB + c2B + nTB);
    prep_cen<<<64, 256, 0, stream>>>(cen, cenb, c2);
    prep_nT<<<256, 256, 0, stream>>>(nrm, nT);
    kexp2<<<Nrows / 128, 512, KEXP2_LDS, stream>>>(x, gam, cenb, c2, Pws, 0);
    g2_8p<<<(Nrows / 256) * 4, 512, 131072, stream>>>(Pws, nT, out, 0, Nrows / 256);
  } else if (ws_size >= cenbB + c2B + nTB + pChB) {
    uint16_t* cenb = (uint16_t*)d_ws;
    float*    c2   = (float*)((char*)d_ws + cenbB);
    uint16_t* nT   = (uint16_t*)((char*)d_ws + cenbB + c2B);
    uint16_t* Pws  = (uint16_t*)((char*)d_ws + cenbB + c2B + nTB);
    prep_cen<<<64, 256, 0, stream>>>(cen, cenb, c2);
    prep_nT<<<256, 256, 0, stream>>>(nrm, nT);
    for (int c = 0; c < NCHUNK; ++c) {
      kexp2<<<CH / 128, 512, KEXP2_LDS, stream>>>(x, gam, cenb, c2, Pws, c * CH);
      g2_8p<<<(CH / 256) * 4, 512, 131072, stream>>>(Pws, nT, out, c * CH, CH / 256);
    }
  } else if (ws_size >= cenbB + c2B + nTB) {
    uint16_t* cenb = (uint16_t*)d_ws;
    float*    c2   = (float*)((char*)d_ws + cenbB);
    uint16_t* nT   = (uint16_t*)((char*)d_ws + cenbB + c2B);
    prep_cen<<<64, 256, 0, stream>>>(cen, cenb, c2);
    prep_nT<<<256, 256, 0, stream>>>(nrm, nT);
    nyst_main<1><<<(Nrows / BMf) * (Cc / BNf), 512, LDS_MAIN, stream>>>(
        x, cen, gam, nrm, cenb, c2, nT, out);
  } else {
    nyst_main<0><<<(Nrows / BMf) * (Cc / BNf), 512, LDS_FB, stream>>>(
        x, cen, gam, nrm, nullptr, nullptr, nullptr, out);
  }
}

// Round 11
// 404.101 us; speedup vs baseline: 5.9361x; 1.0138x over previous
//
#include <hip/hip_runtime.h>
#include <stdint.h>

typedef float    f32x4  __attribute__((ext_vector_type(4)));
typedef __bf16   bf16x8 __attribute__((ext_vector_type(8)));
typedef uint16_t u16x8  __attribute__((ext_vector_type(8)));
typedef uint16_t u16x4  __attribute__((ext_vector_type(4)));

static __device__ __forceinline__ f32x4 mfma_bf16(bf16x8 a, bf16x8 b, f32x4 c) {
  return __builtin_amdgcn_mfma_f32_16x16x32_bf16(a, b, c, 0, 0, 0);
}
// fp32 -> bf16 round-to-nearest-even
static __device__ __forceinline__ uint16_t f2bf(float f) {
  uint32_t u = __builtin_bit_cast(uint32_t, f);
  u += 0x7fffu + ((u >> 16) & 1u);
  return (uint16_t)(u >> 16);
}
// async global->LDS, 16B per lane (gfx950). dest must be linear-in-lane.
static __device__ __forceinline__ void gload16(const void* src, void* lds) {
  __builtin_amdgcn_global_load_lds(
      (const __attribute__((address_space(1))) void*)src,
      (__attribute__((address_space(3))) void*)lds, 16, 0, 0);
}

constexpr int Nrows = 131072;
constexpr int Dk    = 128;
constexpr int Cc    = 1024;
constexpr int CH     = 16384;          // rows per chunk (mid-ws fallback)
constexpr int NCHUNK = Nrows / CH;     // 8
// fused fallback (R5) geometry
constexpr int BMf   = 64;
constexpr int BNf   = 256;
constexpr int KBf   = 128;
constexpr int XBYTES = BMf * Dk * 2;
constexpr int PBYTES = BMf * KBf * 2;
constexpr int LDS_MAIN = XBYTES + PBYTES + BMf * 4;
constexpr int LDS_FB   = LDS_MAIN + Cc * 4;
constexpr int KEXP2_LDS = 32768 * 3 + 34816 + 512;   // 133632

// ---------------------------------------------------------------------------
// Prep A: centers -> bf16 [C][D], and c2[C]
// ---------------------------------------------------------------------------
__global__ void prep_cen(const float* __restrict__ cen,
                         uint16_t* __restrict__ cenb,
                         float* __restrict__ c2) {
  const int t = threadIdx.x;
  const int row = blockIdx.x * 16 + (t >> 4);
  const int q = t & 15;
  const float* src = cen + (size_t)row * Dk + q * 8;
  f32x4 v0 = *(const f32x4*)src;
  f32x4 v1 = *(const f32x4*)(src + 4);
  u16x8 h;
  float ss = 0.f;
#pragma unroll
  for (int i = 0; i < 4; ++i) {
    h[i]     = f2bf(v0[i]); ss += v0[i] * v0[i];
    h[i + 4] = f2bf(v1[i]); ss += v1[i] * v1[i];
  }
  *(u16x8*)(cenb + (size_t)row * Dk + q * 8) = h;
  ss += __shfl_xor(ss, 1);
  ss += __shfl_xor(ss, 2);
  ss += __shfl_xor(ss, 4);
  ss += __shfl_xor(ss, 8);
  if (q == 0) c2[row] = ss;
}

// ---------------------------------------------------------------------------
// Prep B: nT[j][c] = bf16(norm[c][j])
// ---------------------------------------------------------------------------
__global__ void prep_nT(const float* __restrict__ nrm, uint16_t* __restrict__ nT) {
  __shared__ float tile[64][65];
  const int jb = blockIdx.x & 15;
  const int cb = blockIdx.x >> 4;
  const int t  = threadIdx.x;
  const int r  = t >> 4;
  const int q  = t & 15;
#pragma unroll
  for (int i = 0; i < 4; ++i) {
    int row = r + i * 16;
    f32x4 v = *(const f32x4*)(nrm + (size_t)(cb * 64 + row) * Cc + jb * 64 + q * 4);
#pragma unroll
    for (int s = 0; s < 4; ++s) tile[row][q * 4 + s] = v[s];
  }
  __syncthreads();
#pragma unroll
  for (int i = 0; i < 4; ++i) {
    int j = r + i * 16;
    u16x4 hs;
#pragma unroll
    for (int s = 0; s < 4; ++s) hs[s] = f2bf(tile[q * 4 + s][j]);
    *(u16x4*)(nT + (size_t)(jb * 64 + j) * Cc + cb * 64 + q * 4) = hs;
  }
}

// ---------------------------------------------------------------------------
// kexp2: one block per 128-row stripe; colb-loop INSIDE (x read once).
// (proven R9/R10: ~74 us, near BW floor) -- unchanged.
// ---------------------------------------------------------------------------
__global__ __launch_bounds__(512, 2) void kexp2(
    const float* __restrict__ x, const float* __restrict__ gam,
    const uint16_t* __restrict__ cenb, const float* __restrict__ c2g,
    uint16_t* __restrict__ P, int row0) {
  extern __shared__ char smem[];
  char*     xB   = smem;                           // [128] rows x 16 chunks, swz
  char*     cB0  = smem + 32768;
  char*     cB1  = smem + 65536;
  uint16_t* pbuf = (uint16_t*)(smem + 98304);      // [128][136] u16 (272B stride)
  float*    x2s  = (float*)(smem + 98304 + 34816); // [128]

  const int tid  = threadIdx.x;
  const int lane = tid & 63;
  const int wid  = tid >> 6;     // 0..7
  const int wr   = wid >> 2;     // 0..1 : 64-row half
  const int wn   = wid & 3;      // 0..3 : 32-col quarter
  const int l15  = lane & 15;
  const int l4   = lane >> 4;
  const int mb   = blockIdx.x;

  auto stage_c = [&](char* db, int ct) {
#pragma unroll
    for (int i = 0; i < 4; ++i) {
      int ch = tid + i * 512;    // 2048 chunks of 16B
      int r  = ch >> 4;
      int c  = ch & 15;
      gload16(cenb + (size_t)(ct * 128 + r) * Dk + ((c ^ (r & 7)) * 8),
              db + ch * 16);
    }
  };
  stage_c(cB0, 0);  // prologue: tile 0 in flight under the x staging below

  // ---- stage x (f32 -> bf16, swizzled) + x2 row sums ----
  const float* xblk = x + (size_t)(row0 + mb * 128) * Dk;
#pragma unroll
  for (int it = 0; it < 4; ++it) {
    int ch = tid + it * 512;
    int r  = ch >> 4;
    int cc = ch & 15;
    const float* src = xblk + r * Dk + cc * 8;
    f32x4 v0 = __builtin_nontemporal_load((const f32x4*)src);
    f32x4 v1 = __builtin_nontemporal_load((const f32x4*)(src + 4));
    u16x8 hh;
    float ss = 0.f;
#pragma unroll
    for (int i = 0; i < 4; ++i) {
      hh[i]     = f2bf(v0[i]); ss += v0[i] * v0[i];
      hh[i + 4] = f2bf(v1[i]); ss += v1[i] * v1[i];
    }
    *(u16x8*)(xB + r * 256 + ((cc ^ (r & 7)) * 16)) = hh;
    ss += __shfl_xor(ss, 1);
    ss += __shfl_xor(ss, 2);
    ss += __shfl_xor(ss, 4);
    ss += __shfl_xor(ss, 8);
    if ((tid & 15) == 0) x2s[r] = ss;
  }

  const float ngam = -gam[0];

  for (int ct = 0; ct < 8; ++ct) {
    char* cC = (ct & 1) ? cB1 : cB0;
    char* cN = (ct & 1) ? cB0 : cB1;
    if (ct < 7) stage_c(cN, ct + 1);
    if (ct == 0 || ct == 7) asm volatile("s_waitcnt vmcnt(4)" ::: "memory");
    else                    asm volatile("s_waitcnt vmcnt(8)" ::: "memory");
    __builtin_amdgcn_s_barrier();

    f32x4 cr[4][2];
#pragma unroll
    for (int m = 0; m < 4; ++m)
#pragma unroll
      for (int n = 0; n < 2; ++n) cr[m][n] = f32x4{0.f, 0.f, 0.f, 0.f};

#pragma unroll
    for (int kk = 0; kk < 4; ++kk) {
      bf16x8 aF[4], bF[2];
#pragma unroll
      for (int m = 0; m < 4; ++m) {
        int row = wr * 64 + m * 16 + l15;
        aF[m] = *(const bf16x8*)(xB + row * 256 +
                                 (((kk * 4 + l4) ^ (row & 7)) * 16));
      }
#pragma unroll
      for (int n = 0; n < 2; ++n) {
        int col = wn * 32 + n * 16 + l15;
        bF[n] = *(const bf16x8*)(cC + col * 256 +
                                 (((kk * 4 + l4) ^ (col & 7)) * 16));
      }
#pragma unroll
      for (int m = 0; m < 4; ++m)
#pragma unroll
        for (int n = 0; n < 2; ++n) cr[m][n] = mfma_bf16(aF[m], bF[n], cr[m][n]);
    }

    float c2v[2];
#pragma unroll
    for (int n = 0; n < 2; ++n) c2v[n] = c2g[ct * 128 + wn * 32 + n * 16 + l15];
#pragma unroll
    for (int m = 0; m < 4; ++m) {
#pragma unroll
      for (int n = 0; n < 2; ++n) {
#pragma unroll
        for (int rr = 0; rr < 4; ++rr) {
          int row = wr * 64 + m * 16 + l4 * 4 + rr;
          float s = fmaxf(fmaf(-2.f, cr[m][n][rr], x2s[row] + c2v[n]), 0.f);
          pbuf[row * 136 + wn * 32 + n * 16 + l15] = f2bf(__expf(ngam * s));
        }
      }
    }
    __builtin_amdgcn_s_barrier();
#pragma unroll
    for (int it = 0; it < 4; ++it) {
      int ch = tid + it * 512;
      int r  = ch >> 4;
      int cc = ch & 15;
      *(u16x8*)(P + (size_t)(mb * 128 + r) * Cc + ct * 128 + cc * 8) =
          *(const u16x8*)((const char*)pbuf + r * 272 + cc * 16);
    }
  }
}

// ---------------------------------------------------------------------------
// g2_8p v4: out = P @ nT^T, 256x256 tile, BK=64, 8 waves (2Mx4N), 128 KB LDS
// double-buffer. MINIMAL-BARRIER schedule from region lifetimes:
//   A(T) buffer read through all 4 phases; B(T) consumed into regs at p0.
//   Per K-tile: vmcnt(4); BARRIER1 [A(T)/B(T) valid, aN free] -> stage A(T+1)
//   -> read bF(8) + p0 MFMAs -> BARRIER2 [bC free] -> stage B(T+2) into bC ->
//   p1..p3 as ONE straight-line region (12 ds_reads + 48 MFMAs, no barriers:
//   compiler software-pipelines A-reads under MFMAs). 2 barriers/K-tile
//   instead of 8. Drain vmcnt(0) only at kt=15.
// ---------------------------------------------------------------------------
__global__ __launch_bounds__(512, 2) void g2_8p(
    const uint16_t* __restrict__ P, const uint16_t* __restrict__ nT,
    float* __restrict__ out, int row0, int mblocks) {
  extern __shared__ char smem[];
  char* a0 = smem;
  char* b0 = smem + 32768;
  char* a1 = smem + 65536;
  char* b1 = smem + 98304;

  const int tid  = threadIdx.x;
  const int lane = tid & 63;
  const int wid  = tid >> 6;      // 0..7
  const int wm   = wid >> 2;      // 0..1
  const int wn   = wid & 3;       // 0..3
  const int l15  = lane & 15;
  const int l4   = lane >> 4;

  // bijective XCD swizzle (nwg % 8 == 0): nb fastest within an XCD's chunk.
  const int nwg  = mblocks * 4;
  const int cpx  = nwg >> 3;
  const int wgid = (blockIdx.x & 7) * cpx + (blockIdx.x >> 3);
  const int nb   = wgid & 3;
  const int mb   = wgid >> 2;

  const uint16_t* Abase = P + (size_t)mb * 256 * Cc;
  const uint16_t* Bbase = nT + (size_t)nb * 256 * Cc;

  f32x4 acc[8][4];
#pragma unroll
  for (int m = 0; m < 8; ++m)
#pragma unroll
    for (int n = 0; n < 4; ++n) acc[m][n] = f32x4{0.f, 0.f, 0.f, 0.f};

  // stage one half-tile (h=0: rows 0-127, h=1: rows 128-255); 2 gloads/thread,
  // source-swizzled (both-sides rule)
  auto stage_half = [&](const uint16_t* gb, char* db, int k0, int h) {
    int ch0 = h * 1024 + tid;
    int ch1 = ch0 + 512;
    int r0 = ch0 >> 3, c0 = ch0 & 7;
    int r1 = ch1 >> 3, c1 = ch1 & 7;
    gload16(gb + (size_t)r0 * Cc + k0 + ((c0 ^ (r0 & 7)) * 8), db + ch0 * 16);
    gload16(gb + (size_t)r1 * Cc + k0 + ((c1 ^ (r1 & 7)) * 8), db + ch1 * 16);
  };

  // prologue: B(0), A(0), B(1). Queue order matters for the counted waits:
  // at kt=0, vmcnt(4) requires B(0)+A(0) landed, allows B(1) in flight.
  stage_half(Bbase, b0, 0, 0);
  stage_half(Bbase, b0, 0, 1);
  stage_half(Abase, a0, 0, 0);
  stage_half(Abase, a0, 0, 1);
  stage_half(Bbase, b1, 64, 0);
  stage_half(Bbase, b1, 64, 1);

  for (int kt = 0; kt < 16; ++kt) {
    const int q = kt & 1;
    char* aC = q ? a1 : a0;
    char* bC = q ? b1 : b0;
    char* aN = q ? a0 : a1;

    // tile boundary: A(kt),B(kt) landed (all but newest 4 = B(kt+1))
    if (kt == 15) asm volatile("s_waitcnt vmcnt(0)" ::: "memory");
    else          asm volatile("s_waitcnt vmcnt(4)" ::: "memory");
    __builtin_amdgcn_s_barrier();                 // BARRIER1

    // aN's last readers (tile kt-1, p1..p3) are all before BARRIER1 -> free
    if (kt + 1 < 16) {
      stage_half(Abase, aN, (kt + 1) * 64, 0);
      stage_half(Abase, aN, (kt + 1) * 64, 1);
    }

    // consume B(kt) into registers (phase 0 only)
    bf16x8 bF[4][2];
#pragma unroll
    for (int n = 0; n < 4; ++n)
#pragma unroll
      for (int kk = 0; kk < 2; ++kk) {
        int row = wn * 64 + n * 16 + l15;
        bF[n][kk] = *(const bf16x8*)(bC + row * 128 +
                                     (((kk * 4 + l4) ^ (row & 7)) * 16));
      }
    {
      bf16x8 aF[2][2];
#pragma unroll
      for (int mm = 0; mm < 2; ++mm)
#pragma unroll
        for (int kk = 0; kk < 2; ++kk) {
          int row = wm * 128 + mm * 16 + l15;
          aF[mm][kk] = *(const bf16x8*)(aC + row * 128 +
                                        (((kk * 4 + l4) ^ (row & 7)) * 16));
        }
      __builtin_amdgcn_s_setprio(1);
#pragma unroll
      for (int mm = 0; mm < 2; ++mm)
#pragma unroll
        for (int n = 0; n < 4; ++n)
#pragma unroll
          for (int kk = 0; kk < 2; ++kk)
            acc[mm][n] = mfma_bf16(aF[mm][kk], bF[n][kk], acc[mm][n]);
      __builtin_amdgcn_s_setprio(0);
    }
    __builtin_amdgcn_s_barrier();                 // BARRIER2: bC free

    // restage bC with B(kt+2) (same parity); lands by tile kt+2's BARRIER1
    if (kt + 2 < 16) {
      stage_half(Bbase, bC, (kt + 2) * 64, 0);
      stage_half(Bbase, bC, (kt + 2) * 64, 1);
    }

    // phases 1..3: straight-line, no barriers -- compiler pipelines reads
    __builtin_amdgcn_s_setprio(1);
#pragma unroll
    for (int p = 1; p < 4; ++p) {
      bf16x8 aF[2][2];
#pragma unroll
      for (int mm = 0; mm < 2; ++mm)
#pragma unroll
        for (int kk = 0; kk < 2; ++kk) {
          int row = wm * 128 + (2 * p + mm) * 16 + l15;
          aF[mm][kk] = *(const bf16x8*)(aC + row * 128 +
                                        (((kk * 4 + l4) ^ (row & 7)) * 16));
        }
#pragma unroll
      for (int mm = 0; mm < 2; ++mm)
#pragma unroll
        for (int n = 0; n < 4; ++n)
#pragma unroll
          for (int kk = 0; kk < 2; ++kk)
            acc[2 * p + mm][n] = mfma_bf16(aF[mm][kk], bF[n][kk], acc[2 * p + mm][n]);
    }
    __builtin_amdgcn_s_setprio(0);
  }

  // epilogue: bounce halves (128 rows x 256 f32 = 128 KB) -> coalesced stores
  float* obuf = (float*)smem;
#pragma unroll
  for (int h = 0; h < 2; ++h) {
    __syncthreads();
    if (wm == h) {
#pragma unroll
      for (int m = 0; m < 8; ++m)
#pragma unroll
        for (int n = 0; n < 4; ++n)
#pragma unroll
          for (int r = 0; r < 4; ++r) {
            int rL = m * 16 + l4 * 4 + r;  // 0..127
            obuf[rL * 256 + wn * 64 + 16 * n + l15] = acc[m][n][r];
          }
    }
    __syncthreads();
#pragma unroll
    for (int i = 0; i < 16; ++i) {
      int ch = tid + i * 512;   // 8192 chunks of 16B
      int rL = ch >> 6;         // 0..127
      int c4 = ch & 63;
      *(f32x4*)(out + (size_t)(row0 + mb * 256 + h * 128 + rL) * Cc +
                nb * 256 + c4 * 4) = *(const f32x4*)(obuf + rL * 256 + c4 * 4);
    }
  }
}

// ---------------------------------------------------------------------------
// Fused fallback (R5) — only used when ws is too small for the split path.
// ---------------------------------------------------------------------------
template <int USE_NT>
__global__ __launch_bounds__(512, 4) void nyst_main(
    const float* __restrict__ x, const float* __restrict__ cen,
    const float* __restrict__ gam, const float* __restrict__ nrm,
    const uint16_t* __restrict__ cenb, const float* __restrict__ c2g,
    const uint16_t* __restrict__ nT, float* __restrict__ out) {
  extern __shared__ char smem[];
  char*  xB  = smem;
  char*  pB  = smem + XBYTES;
  float* x2s = (float*)(smem + XBYTES + PBYTES);
  float* c2s = (float*)(smem + LDS_MAIN);

  const int tid  = threadIdx.x;
  const int lane = tid & 63;
  const int wid  = tid >> 6;
  const int wr   = wid >> 2;
  const int wc   = wid & 3;
  const int xcd  = blockIdx.x & 7;
  const int bi   = blockIdx.x >> 3;
  const int colb = xcd >> 1;
  const int rowb = (bi << 1) | (xcd & 1);
  const int l15  = lane & 15;
  const int l4   = lane >> 4;

  const float* xblk = x + (size_t)rowb * BMf * Dk;

#pragma unroll
  for (int it = 0; it < 2; ++it) {
    int ch = tid + it * 512;
    int r  = ch >> 4;
    int cc = ch & 15;
    const float* src = xblk + r * Dk + cc * 8;
    f32x4 v0 = __builtin_nontemporal_load((const f32x4*)src);
    f32x4 v1 = __builtin_nontemporal_load((const f32x4*)(src + 4));
    u16x8 hh;
    float ss = 0.f;
#pragma unroll
    for (int i = 0; i < 4; ++i) {
      hh[i]     = f2bf(v0[i]); ss += v0[i] * v0[i];
      hh[i + 4] = f2bf(v1[i]); ss += v1[i] * v1[i];
    }
    int off = (r * 256 + cc * 16) ^ ((r & 7) << 4);
    *(u16x8*)(xB + off) = hh;
    ss += __shfl_xor(ss, 1);
    ss += __shfl_xor(ss, 2);
    ss += __shfl_xor(ss, 4);
    ss += __shfl_xor(ss, 8);
    if ((tid & 15) == 0) x2s[r] = ss;
  }
  if (!USE_NT) {
#pragma unroll
    for (int rr = 0; rr < 2; ++rr) {
      int r = tid + rr * 512;
      const float* src = cen + (size_t)r * Dk;
      float ss = 0.f;
      for (int k = 0; k < Dk / 4; ++k) {
        f32x4 v = *(const f32x4*)(src + 4 * k);
        ss += v[0] * v[0] + v[1] * v[1] + v[2] * v[2] + v[3] * v[3];
      }
      c2s[r] = ss;
    }
  }
  __syncthreads();

  const float ngam = -gam[0];
  f32x4 zero4 = {0.f, 0.f, 0.f, 0.f};
  f32x4 acc[2][4];
#pragma unroll
  for (int m = 0; m < 2; ++m)
#pragma unroll
    for (int n = 0; n < 4; ++n) acc[m][n] = zero4;

  for (int c0 = 0; c0 < Cc; c0 += KBf) {
    f32x4 cr[2][2];
#pragma unroll
    for (int g = 0; g < 2; ++g)
#pragma unroll
      for (int m = 0; m < 2; ++m) cr[g][m] = zero4;

#pragma unroll
    for (int kk = 0; kk < 4; ++kk) {
      bf16x8 b0, b1;
      if (USE_NT) {
        int c0col = c0 + 16 * wc + l15;
        b0 = *(const bf16x8*)(cenb + (size_t)c0col * Dk + kk * 32 + l4 * 8);
        b1 = *(const bf16x8*)(cenb + (size_t)(c0col + 64) * Dk + kk * 32 + l4 * 8);
      } else {
#pragma unroll
        for (int g = 0; g < 2; ++g) {
          int ccol = c0 + g * 64 + 16 * wc + l15;
          const float* cb_ = cen + (size_t)ccol * Dk + kk * 32 + l4 * 8;
          f32x4 v0 = *(const f32x4*)cb_;
          f32x4 v1 = *(const f32x4*)(cb_ + 4);
          u16x8 tt;
#pragma unroll
          for (int i = 0; i < 4; ++i) { tt[i] = f2bf(v0[i]); tt[i + 4] = f2bf(v1[i]); }
          if (g == 0) b0 = __builtin_bit_cast(bf16x8, tt);
          else        b1 = __builtin_bit_cast(bf16x8, tt);
        }
      }
#pragma unroll
      for (int m = 0; m < 2; ++m) {
        int row = 32 * wr + 16 * m + l15;
        int off = (row * 256 + kk * 64 + l4 * 16) ^ ((row & 7) << 4);
        bf16x8 a = *(const bf16x8*)(xB + off);
        cr[0][m] = mfma_bf16(a, b0, cr[0][m]);
        cr[1][m] = mfma_bf16(a, b1, cr[1][m]);
      }
    }

    __syncthreads();
#pragma unroll
    for (int g = 0; g < 2; ++g) {
      int ccol = c0 + g * 64 + 16 * wc + l15;
      float c2v = USE_NT ? c2g[ccol] : c2s[ccol];
#pragma unroll
      for (int m = 0; m < 2; ++m) {
#pragma unroll
        for (int r = 0; r < 4; ++r) {
          int row = 32 * wr + 16 * m + l4 * 4 + r;
          float s = fmaxf(fmaf(-2.f, cr[g][m][r], x2s[row] + c2v), 0.f);
          float p = __expf(ngam * s);
          int off = (row * 256 + (g * 64 + 16 * wc + l15) * 2) ^ ((row & 7) << 4);
          *(uint16_t*)(pB + off) = f2bf(p);
        }
      }
    }
    __syncthreads();

#pragma unroll
    for (int kk = 0; kk < 4; ++kk) {
      bf16x8 pa[2];
#pragma unroll
      for (int m = 0; m < 2; ++m) {
        int row = 32 * wr + 16 * m + l15;
        int off = (row * 256 + kk * 64 + l4 * 16) ^ ((row & 7) << 4);
        pa[m] = *(const bf16x8*)(pB + off);
      }
      int krow = c0 + kk * 32 + l4 * 8;
#pragma unroll
      for (int n = 0; n < 4; ++n) {
        int j = colb * BNf + wc * 64 + 16 * n + l15;
        bf16x8 bm;
        if (USE_NT) {
          bm = *(const bf16x8*)(nT + (size_t)j * Cc + krow);
        } else {
          u16x8 tt;
#pragma unroll
          for (int i = 0; i < 8; ++i) tt[i] = f2bf(nrm[(size_t)(krow + i) * Cc + j]);
          bm = __builtin_bit_cast(bf16x8, tt);
        }
        acc[0][n] = mfma_bf16(pa[0], bm, acc[0][n]);
        acc[1][n] = mfma_bf16(pa[1], bm, acc[1][n]);
      }
    }
  }

  float* outBuf = (float*)smem;
  const int orow0 = rowb * BMf;
#pragma unroll
  for (int h = 0; h < 2; ++h) {
    __syncthreads();
    if (wr == h) {
#pragma unroll
      for (int m = 0; m < 2; ++m) {
#pragma unroll
        for (int n = 0; n < 4; ++n) {
#pragma unroll
          for (int r = 0; r < 4; ++r) {
            int rL = 16 * m + l4 * 4 + r;
            outBuf[rL * 256 + wc * 64 + 16 * n + l15] = acc[m][n][r];
          }
        }
      }
    }
    __syncthreads();
#pragma unroll
    for (int i = 0; i < 4; ++i) {
      int ch = tid + 512 * i;
      int rL = ch >> 6;
      int c4 = ch & 63;
      f32x4 v = *(const f32x4*)(outBuf + rL * 256 + c4 * 4);
      *(f32x4*)(out + (size_t)(orow0 + 32 * h + rL) * Cc + colb * BNf + c4 * 4) = v;
    }
  }
}

// ---------------------------------------------------------------------------
extern "C" void kernel_launch(void* const* d_in, const int* in_sizes, int n_in,
                              void* d_out, int out_size, void* d_ws, size_t ws_size,
                              hipStream_t stream) {
  const float* x   = (const float*)d_in[0];  // [131072,128]
  const float* cen = (const float*)d_in[1];  // [1024,128]
  const float* gam = (const float*)d_in[2];  // [1]
  const float* nrm = (const float*)d_in[3];  // [1024,1024]
  float* out = (float*)d_out;

  const size_t cenbB = (size_t)Cc * Dk * 2;            // 256 KB
  const size_t c2B   = (size_t)Cc * 4;                 // 4 KB
  const size_t nTB   = (size_t)Cc * Cc * 2;            // 2 MB
  const size_t pFull = (size_t)Nrows * Cc * 2;         // 268 MB
  const size_t pChB  = (size_t)CH * Cc * 2;            // 33.5 MB

  if (ws_size >= cenbB + c2B + nTB + pFull) {
    uint16_t* cenb = (uint16_t*)d_ws;
    float*    c2   = (float*)((char*)d_ws + cenbB);
    uint16_t* nT   = (uint16_t*)((char*)d_ws + cenbB + c2B);
    uint16_t* Pws  = (uint16_t*)((char*)d_ws + cenbB + c2B + nTB);
    prep_cen<<<64, 256, 0, stream>>>(cen, cenb, c2);
    prep_nT<<<256, 256, 0, stream>>>(nrm, nT);
    kexp2<<<Nrows / 128, 512, KEXP2_LDS, stream>>>(x, gam, cenb, c2, Pws, 0);
    g2_8p<<<(Nrows / 256) * 4, 512, 131072, stream>>>(Pws, nT, out, 0, Nrows / 256);
  } else if (ws_size >= cenbB + c2B + nTB + pChB) {
    uint16_t* cenb = (uint16_t*)d_ws;
    float*    c2   = (float*)((char*)d_ws + cenbB);
    uint16_t* nT   = (uint16_t*)((char*)d_ws + cenbB + c2B);
    uint16_t* Pws  = (uint16_t*)((char*)d_ws + cenbB + c2B + nTB);
    prep_cen<<<64, 256, 0, stream>>>(cen, cenb, c2);
    prep_nT<<<256, 256, 0, stream>>>(nrm, nT);
    for (int c = 0; c < NCHUNK; ++c) {
      kexp2<<<CH / 128, 512, KEXP2_LDS, stream>>>(x, gam, cenb, c2, Pws, c * CH);
      g2_8p<<<(CH / 256) * 4, 512, 131072, stream>>>(Pws, nT, out, c * CH, CH / 256);
    }
  } else if (ws_size >= cenbB + c2B + nTB) {
    uint16_t* cenb = (uint16_t*)d_ws;
    float*    c2   = (float*)((char*)d_ws + cenbB);
    uint16_t* nT   = (uint16_t*)((char*)d_ws + cenbB + c2B);
    prep_cen<<<64, 256, 0, stream>>>(cen, cenb, c2);
    prep_nT<<<256, 256, 0, stream>>>(nrm, nT);
    nyst_main<1><<<(Nrows / BMf) * (Cc / BNf), 512, LDS_MAIN, stream>>>(
        x, cen, gam, nrm, cenb, c2, nT, out);
  } else {
    nyst_main<0><<<(Nrows / BMf) * (Cc / BNf), 512, LDS_FB, stream>>>(
        x, cen, gam, nrm, nullptr, nullptr, nullptr, out);
  }
}